// Round 3
// baseline (749.320 us; speedup 1.0000x reference)
//
#include <hip/hip_runtime.h>
#include <hip/hip_bf16.h>
#include <math.h>

#define HID 128
#define HEADS 8
#define INDIM 64

// ================= CSR build (by dst) =================

__global__ void count_kernel(const int* __restrict__ ei, int* __restrict__ deg, int E, int EE) {
    int e = blockIdx.x * blockDim.x + threadIdx.x;
    if (e >= EE) return;
    int dst = (e < E) ? ei[E + e] : (e - E);
    atomicAdd(&deg[dst], 1);
}

__global__ void block_sum_kernel(const int* __restrict__ deg, int* __restrict__ partials, int N) {
    __shared__ int sdata[4];
    int t = threadIdx.x;
    int i = blockIdx.x * 256 + t;
    int v = (i < N) ? deg[i] : 0;
#pragma unroll
    for (int m = 32; m >= 1; m >>= 1) v += __shfl_xor(v, m, 64);
    if ((t & 63) == 0) sdata[t >> 6] = v;
    __syncthreads();
    if (t == 0) partials[blockIdx.x] = sdata[0] + sdata[1] + sdata[2] + sdata[3];
}

__global__ void scan_partials_kernel(int* __restrict__ partials, int nb) {
    int lane = threadIdx.x;  // 64 threads
    int carry = 0;
    for (int base = 0; base < nb; base += 64) {
        int i = base + lane;
        int v = (i < nb) ? partials[i] : 0;
        int orig = v;
#pragma unroll
        for (int off = 1; off < 64; off <<= 1) {
            int x = __shfl_up(v, off, 64);
            if (lane >= off) v += x;
        }
        if (i < nb) partials[i] = v - orig + carry;
        carry += __shfl(v, 63, 64);
    }
}

__global__ void rowptr_kernel(const int* __restrict__ deg, const int* __restrict__ partials,
                              int* __restrict__ rowptr, int* __restrict__ woff, int N, int EE) {
    __shared__ int tmp[256];
    int t = threadIdx.x;
    int i = blockIdx.x * 256 + t;
    int v = (i < N) ? deg[i] : 0;
    tmp[t] = v;
    __syncthreads();
#pragma unroll
    for (int off = 1; off < 256; off <<= 1) {
        int x = (t >= off) ? tmp[t - off] : 0;
        __syncthreads();
        tmp[t] += x;
        __syncthreads();
    }
    int excl = tmp[t] - v + partials[blockIdx.x];
    if (i < N) { rowptr[i] = excl; woff[i] = excl; }
    if (blockIdx.x == 0 && t == 0) rowptr[N] = EE;
}

__global__ void scatter_kernel(const int* __restrict__ ei, int* __restrict__ woff,
                               int* __restrict__ esrc, int E, int EE) {
    int e = blockIdx.x * blockDim.x + threadIdx.x;
    if (e >= EE) return;
    int src, dst;
    if (e < E) { src = ei[e]; dst = ei[E + e]; } else { src = dst = e - E; }
    int slot = atomicAdd(&woff[dst], 1);
    esrc[slot] = src;
}

// graph boundaries: batch is sorted; gstart[g] = first n with batch[n] >= g
__global__ void gstart_kernel(const int* __restrict__ batch, int* __restrict__ gstart,
                              int N, int G) {
    int g = blockIdx.x * blockDim.x + threadIdx.x;
    if (g > G) return;
    int lo = 0, hi = N;
    while (lo < hi) {
        int mid = (lo + hi) >> 1;
        if (batch[mid] < g) lo = mid + 1; else hi = mid;
    }
    gstart[g] = lo;
}

// ================= embed: h = x @ emb_W + emb_b + ntype_emb[node_types] =================
// 8 nodes per 128-thread block; thread t owns output channel t.
__global__ void embed_kernel(const float* __restrict__ x, const float* __restrict__ W,
                             const float* __restrict__ b, const float* __restrict__ nemb,
                             const int* __restrict__ ntypes, float* __restrict__ h, int N) {
    int t = threadIdx.x;
    int n0 = blockIdx.x * 8;
    __shared__ float xr[8][INDIM];
    for (int i = t; i < 8 * INDIM; i += 128) {
        int j = i >> 6, k = i & 63;
        int n = n0 + j;
        xr[j][k] = (n < N) ? x[n * INDIM + k] : 0.f;
    }
    __syncthreads();
    float acc[8] = {0.f};
#pragma unroll 8
    for (int k = 0; k < INDIM; ++k) {
        float w = W[k * HID + t];
#pragma unroll
        for (int j = 0; j < 8; ++j) acc[j] += xr[j][k] * w;
    }
    float bb = b[t];
#pragma unroll
    for (int j = 0; j < 8; ++j) {
        int n = n0 + j;
        if (n < N) {
            int nt = ntypes[n];
            h[n * HID + t] = acc[j] + bb + nemb[nt * HID + t];
        }
    }
}

// ================= GAT projection + attention logits (8 nodes/block) =================
__global__ void gemm_alpha_kernel(const float* __restrict__ h, const float* __restrict__ W,
                                  const float* __restrict__ asrc, const float* __restrict__ adst,
                                  float* __restrict__ hp, float* __restrict__ als,
                                  float* __restrict__ ald, int N) {
    int t = threadIdx.x;
    int n0 = blockIdx.x * 8;
    __shared__ float hr[8][HID];
#pragma unroll
    for (int j = 0; j < 8; ++j) {
        int n = n0 + j;
        hr[j][t] = (n < N) ? h[n * HID + t] : 0.f;
    }
    __syncthreads();
    float acc[8] = {0.f};
#pragma unroll 8
    for (int k = 0; k < HID; ++k) {
        float w = W[k * HID + t];
#pragma unroll
        for (int j = 0; j < 8; ++j) acc[j] += hr[j][k] * w;
    }
    float as = asrc[t], ad = adst[t];
#pragma unroll
    for (int j = 0; j < 8; ++j) {
        int n = n0 + j;
        if (n >= N) continue;
        hp[n * HID + t] = acc[j];
        float ps = acc[j] * as;
        float pd = acc[j] * ad;
#pragma unroll
        for (int m = 8; m >= 1; m >>= 1) {
            ps += __shfl_xor(ps, m, 64);
            pd += __shfl_xor(pd, m, 64);
        }
        if ((t & 15) == 0) {
            int hd = t >> 4;
            als[n * HEADS + hd] = ps;
            ald[n * HEADS + hd] = pd;
        }
    }
}

// ================= fused aggregate: softmax + message sum + bias + LN + residual relu ===========
__global__ void gat_aggregate_kernel(const int* __restrict__ rowptr, const int* __restrict__ esrc,
                                     const float* __restrict__ als, const float* __restrict__ ald,
                                     const float* __restrict__ hp, const float* __restrict__ gb,
                                     const float* __restrict__ lg, const float* __restrict__ lb,
                                     float* __restrict__ h, int N) {
    int wave = threadIdx.x >> 6;
    int lane = threadIdx.x & 63;
    int n = blockIdx.x * 4 + wave;
    if (n >= N) return;
    int hd0 = lane >> 4, hd1 = hd0 + 4;
    int c0 = lane, c1 = lane + 64;
    float ad0 = ald[n * HEADS + hd0];
    float ad1 = ald[n * HEADS + hd1];
    int row = rowptr[n], end = rowptr[n + 1];
    float acc0 = 0.f, acc1 = 0.f, sw0 = 0.f, sw1 = 0.f;
    int src_next = esrc[row];
    for (int i = row; i < end; ++i) {
        int src = src_next;
        if (i + 1 < end) src_next = esrc[i + 1];
        float l0 = als[src * HEADS + hd0] + ad0;
        float l1 = als[src * HEADS + hd1] + ad1;
        l0 = l0 > 0.f ? l0 : 0.2f * l0;
        l1 = l1 > 0.f ? l1 : 0.2f * l1;
        float w0 = __expf(l0), w1 = __expf(l1);
        sw0 += w0; sw1 += w1;
        acc0 += w0 * hp[src * HID + c0];
        acc1 += w1 * hp[src * HID + c1];
    }
    float v0 = acc0 / sw0 + gb[c0];
    float v1 = acc1 / sw1 + gb[c1];
    float sum = v0 + v1;
#pragma unroll
    for (int m = 32; m >= 1; m >>= 1) sum += __shfl_xor(sum, m, 64);
    float mu = sum * (1.f / 128.f);
    float d0 = v0 - mu, d1 = v1 - mu;
    float sq = d0 * d0 + d1 * d1;
#pragma unroll
    for (int m = 32; m >= 1; m >>= 1) sq += __shfl_xor(sq, m, 64);
    float inv = rsqrtf(sq * (1.f / 128.f) + 1e-5f);
    float y0 = d0 * inv * lg[c0] + lb[c0];
    float y1 = d1 * inv * lg[c1] + lb[c1];
    float r0 = y0 + h[n * HID + c0];
    float r1 = y1 + h[n * HID + c1];
    h[n * HID + c0] = r0 > 0.f ? r0 : 0.f;
    h[n * HID + c1] = r1 > 0.f ? r1 : 0.f;
}

// ================= global attention scores (8 nodes/block) =================
__global__ void score_kernel(const float* __restrict__ h, const float* __restrict__ W1,
                             const float* __restrict__ b1, const float* __restrict__ W2,
                             const float* __restrict__ b2, float* __restrict__ escore, int N) {
    int t = threadIdx.x;
    int n0 = blockIdx.x * 8;
    __shared__ float hr[8][HID];
    __shared__ float part[8][2];
#pragma unroll
    for (int j = 0; j < 8; ++j) {
        int n = n0 + j;
        hr[j][t] = (n < N) ? h[n * HID + t] : 0.f;
    }
    __syncthreads();
    float acc[8];
#pragma unroll
    for (int j = 0; j < 8; ++j) acc[j] = b1[t];
#pragma unroll 8
    for (int k = 0; k < HID; ++k) {
        float w = W1[k * HID + t];
#pragma unroll
        for (int j = 0; j < 8; ++j) acc[j] += hr[j][k] * w;
    }
    float w2 = W2[t];
#pragma unroll
    for (int j = 0; j < 8; ++j) {
        float v = tanhf(acc[j]) * w2;
#pragma unroll
        for (int m = 32; m >= 1; m >>= 1) v += __shfl_xor(v, m, 64);
        if ((t & 63) == 0) part[j][t >> 6] = v;
    }
    __syncthreads();
    if (t < 8) {
        int n = n0 + t;
        if (n < N) escore[n] = expf(part[t][0] + part[t][1] + b2[0]);
    }
}

// ================= per-graph pooling (batch sorted -> contiguous segments, NO atomics) ==========
// one block per graph; thread t owns channel t.
__global__ void pool_graph_kernel(const float* __restrict__ h, const float* __restrict__ escore,
                                  const int* __restrict__ gstart, float* __restrict__ sums,
                                  float* __restrict__ attpart, float* __restrict__ Zpart,
                                  float* __restrict__ cnts, int G) {
    int g = blockIdx.x;
    int t = threadIdx.x;  // 0..127
    int s = gstart[g], e = gstart[g + 1];
    float msum = 0.f, asum = 0.f, z = 0.f;
    for (int n = s; n < e; ++n) {
        float hv = h[n * HID + t];
        float es = escore[n];
        msum += hv;
        asum += es * hv;
        if (t == 0) z += es;
    }
    sums[g * HID + t] = msum;
    attpart[g * HID + t] = asum;
    if (t == 0) { Zpart[g] = z; cnts[g] = (float)(e - s); }
}

// reduce attention partials across graphs -> hgZ[0..127] numerator, hgZ[128] = Z
__global__ void att_reduce_kernel(const float* __restrict__ attpart, const float* __restrict__ Zpart,
                                  float* __restrict__ hgZ, int G) {
    int t = threadIdx.x;  // 0..127
    float a = 0.f, z = 0.f;
    for (int g = t & 127; 0; ) break;
    for (int g = 0; g < G; ++g) a += attpart[g * HID + t];
    for (int g = t; g < G; g += 128) z += Zpart[g];
    hgZ[t] = a;
    // block-reduce z across 128 threads
    __shared__ float zs[2];
#pragma unroll
    for (int m = 32; m >= 1; m >>= 1) z += __shfl_xor(z, m, 64);
    if ((t & 63) == 0) zs[t >> 6] = z;
    __syncthreads();
    if (t == 0) hgZ[HID] = zs[0] + zs[1];
}

// ================= classifier head =================
__global__ void head_kernel(const float* __restrict__ hgZ, const float* __restrict__ sums,
                            const float* __restrict__ cnts, const float* __restrict__ W1,
                            const float* __restrict__ b1, const float* __restrict__ W2,
                            const float* __restrict__ b2, float* __restrict__ out, int G) {
    int g = blockIdx.x;
    int t = threadIdx.x;
    __shared__ float hr[HID];
    __shared__ float part[2];
    float Z = hgZ[HID];
    float cnt = cnts[g];
    cnt = cnt > 1.f ? cnt : 1.f;
    hr[t] = hgZ[t] / Z + sums[g * HID + t] / cnt;
    __syncthreads();
    float acc = b1[t];
#pragma unroll 8
    for (int k = 0; k < HID; ++k) acc += hr[k] * W1[k * HID + t];
    acc = acc > 0.f ? acc : 0.f;
    float v = acc * W2[t];
#pragma unroll
    for (int m = 32; m >= 1; m >>= 1) v += __shfl_xor(v, m, 64);
    if ((t & 63) == 0) part[t >> 6] = v;
    __syncthreads();
    if (t == 0) out[g] = part[0] + part[1] + b2[0];
}

extern "C" void kernel_launch(void* const* d_in, const int* in_sizes, int n_in,
                              void* d_out, int out_size, void* d_ws, size_t ws_size,
                              hipStream_t stream) {
    const float* x        = (const float*)d_in[0];
    const int*   ei       = (const int*)d_in[1];
    const int*   ntypes   = (const int*)d_in[2];
    const int*   batch    = (const int*)d_in[3];
    const float* emb_W    = (const float*)d_in[4];
    const float* emb_b    = (const float*)d_in[5];
    const float* nemb     = (const float*)d_in[6];
    const float* gat_W    = (const float*)d_in[7];
    const float* att_src  = (const float*)d_in[8];
    const float* att_dst  = (const float*)d_in[9];
    const float* gat_b    = (const float*)d_in[10];
    const float* ln_g     = (const float*)d_in[11];
    const float* ln_b     = (const float*)d_in[12];
    const float* ga_W1    = (const float*)d_in[13];
    const float* ga_b1    = (const float*)d_in[14];
    const float* ga_W2    = (const float*)d_in[15];
    const float* ga_b2    = (const float*)d_in[16];
    const float* cls_W1   = (const float*)d_in[17];
    const float* cls_b1   = (const float*)d_in[18];
    const float* cls_W2   = (const float*)d_in[19];
    const float* cls_b2   = (const float*)d_in[20];
    float* out = (float*)d_out;

    const int N  = in_sizes[2];
    const int E  = in_sizes[1] / 2;
    const int EE = E + N;
    const int G  = out_size;
    const int NB = (N + 255) / 256;

    float* ws      = (float*)d_ws;
    float* h       = ws;                               // N*128
    float* hp      = h + (size_t)N * HID;              // N*128
    float* als     = hp + (size_t)N * HID;             // N*8
    float* ald     = als + (size_t)N * HEADS;          // N*8
    float* escore  = ald + (size_t)N * HEADS;          // N
    float* sums    = escore + N;                       // G*128
    float* attpart = sums + (size_t)G * HID;           // G*128
    float* Zpart   = attpart + (size_t)G * HID;        // G
    float* cnts    = Zpart + G;                        // G
    float* hgZ     = cnts + G;                         // 129
    int*   ibase   = (int*)(hgZ + HID + 1);
    int*   rowptr  = ibase;                            // N+1
    int*   woff    = rowptr + (N + 1);                 // N
    int*   deg     = woff + N;                         // N
    int*   esrc    = deg + N;                          // EE
    int*   partials= esrc + EE;                        // NB
    int*   gstart  = partials + NB;                    // G+1

    // ---- CSR build ----
    hipMemsetAsync(deg, 0, (size_t)N * sizeof(int), stream);
    count_kernel<<<(EE + 255) / 256, 256, 0, stream>>>(ei, deg, E, EE);
    block_sum_kernel<<<NB, 256, 0, stream>>>(deg, partials, N);
    scan_partials_kernel<<<1, 64, 0, stream>>>(partials, NB);
    rowptr_kernel<<<NB, 256, 0, stream>>>(deg, partials, rowptr, woff, N, EE);
    scatter_kernel<<<(EE + 255) / 256, 256, 0, stream>>>(ei, woff, esrc, E, EE);
    gstart_kernel<<<(G + 64) / 64, 64, 0, stream>>>(batch, gstart, N, G);

    // ---- network ----
    embed_kernel<<<(N + 7) / 8, 128, 0, stream>>>(x, emb_W, emb_b, nemb, ntypes, h, N);

    for (int l = 0; l < 3; ++l) {
        gemm_alpha_kernel<<<(N + 7) / 8, 128, 0, stream>>>(
            h, gat_W + (size_t)l * HID * HID, att_src + l * HID, att_dst + l * HID,
            hp, als, ald, N);
        gat_aggregate_kernel<<<(N + 3) / 4, 256, 0, stream>>>(
            rowptr, esrc, als, ald, hp, gat_b + l * HID, ln_g + l * HID, ln_b + l * HID, h, N);
    }

    score_kernel<<<(N + 7) / 8, 128, 0, stream>>>(h, ga_W1, ga_b1, ga_W2, ga_b2, escore, N);
    pool_graph_kernel<<<G, 128, 0, stream>>>(h, escore, gstart, sums, attpart, Zpart, cnts, G);
    att_reduce_kernel<<<1, 128, 0, stream>>>(attpart, Zpart, hgZ, G);
    head_kernel<<<G, 128, 0, stream>>>(hgZ, sums, cnts, cls_W1, cls_b1, cls_W2, cls_b2, out, G);
}

// Round 4
// 667.947 us; speedup vs baseline: 1.1218x; 1.1218x over previous
//
#include <hip/hip_runtime.h>
#include <hip/hip_bf16.h>
#include <math.h>

#define HID 128
#define HEADS 8
#define INDIM 64

__device__ __forceinline__ unsigned short f2bf(float v) {
    unsigned u = __float_as_uint(v);
    u += 0x7FFFu + ((u >> 16) & 1u);   // RNE
    return (unsigned short)(u >> 16);
}
__device__ __forceinline__ float bf2f(unsigned short b) {
    return __uint_as_float(((unsigned)b) << 16);
}

// ================= CSR build (by dst) =================

__global__ void count_kernel(const int* __restrict__ ei, int* __restrict__ deg, int E, int EE) {
    int e = blockIdx.x * blockDim.x + threadIdx.x;
    if (e >= EE) return;
    int dst = (e < E) ? ei[E + e] : (e - E);
    atomicAdd(&deg[dst], 1);
}

__global__ void block_sum_kernel(const int* __restrict__ deg, int* __restrict__ partials, int N) {
    __shared__ int sdata[4];
    int t = threadIdx.x;
    int i = blockIdx.x * 256 + t;
    int v = (i < N) ? deg[i] : 0;
#pragma unroll
    for (int m = 32; m >= 1; m >>= 1) v += __shfl_xor(v, m, 64);
    if ((t & 63) == 0) sdata[t >> 6] = v;
    __syncthreads();
    if (t == 0) partials[blockIdx.x] = sdata[0] + sdata[1] + sdata[2] + sdata[3];
}

__global__ void scan_partials_kernel(int* __restrict__ partials, int nb) {
    int lane = threadIdx.x;  // 64 threads
    int carry = 0;
    for (int base = 0; base < nb; base += 64) {
        int i = base + lane;
        int v = (i < nb) ? partials[i] : 0;
        int orig = v;
#pragma unroll
        for (int off = 1; off < 64; off <<= 1) {
            int x = __shfl_up(v, off, 64);
            if (lane >= off) v += x;
        }
        if (i < nb) partials[i] = v - orig + carry;
        carry += __shfl(v, 63, 64);
    }
}

__global__ void rowptr_kernel(const int* __restrict__ deg, const int* __restrict__ partials,
                              int* __restrict__ rowptr, int* __restrict__ woff, int N, int EE) {
    __shared__ int tmp[256];
    int t = threadIdx.x;
    int i = blockIdx.x * 256 + t;
    int v = (i < N) ? deg[i] : 0;
    tmp[t] = v;
    __syncthreads();
#pragma unroll
    for (int off = 1; off < 256; off <<= 1) {
        int x = (t >= off) ? tmp[t - off] : 0;
        __syncthreads();
        tmp[t] += x;
        __syncthreads();
    }
    int excl = tmp[t] - v + partials[blockIdx.x];
    if (i < N) { rowptr[i] = excl; woff[i] = excl; }
    if (blockIdx.x == 0 && t == 0) rowptr[N] = EE;
}

__global__ void scatter_kernel(const int* __restrict__ ei, int* __restrict__ woff,
                               int* __restrict__ esrc, int E, int EE) {
    int e = blockIdx.x * blockDim.x + threadIdx.x;
    if (e >= EE) return;
    int src, dst;
    if (e < E) { src = ei[e]; dst = ei[E + e]; } else { src = dst = e - E; }
    int slot = atomicAdd(&woff[dst], 1);
    esrc[slot] = src;
}

__global__ void gstart_kernel(const int* __restrict__ batch, int* __restrict__ gstart,
                              int N, int G) {
    int g = blockIdx.x * blockDim.x + threadIdx.x;
    if (g > G) return;
    int lo = 0, hi = N;
    while (lo < hi) {
        int mid = (lo + hi) >> 1;
        if (batch[mid] < g) lo = mid + 1; else hi = mid;
    }
    gstart[g] = lo;
}

// ================= embed =================
__global__ void embed_kernel(const float* __restrict__ x, const float* __restrict__ W,
                             const float* __restrict__ b, const float* __restrict__ nemb,
                             const int* __restrict__ ntypes, float* __restrict__ h, int N) {
    int t = threadIdx.x;
    int n0 = blockIdx.x * 8;
    __shared__ float xr[8][INDIM];
    for (int i = t; i < 8 * INDIM; i += 128) {
        int j = i >> 6, k = i & 63;
        int n = n0 + j;
        xr[j][k] = (n < N) ? x[n * INDIM + k] : 0.f;
    }
    __syncthreads();
    float acc[8] = {0.f};
#pragma unroll 8
    for (int k = 0; k < INDIM; ++k) {
        float w = W[k * HID + t];
#pragma unroll
        for (int j = 0; j < 8; ++j) acc[j] += xr[j][k] * w;
    }
    float bb = b[t];
#pragma unroll
    for (int j = 0; j < 8; ++j) {
        int n = n0 + j;
        if (n < N) {
            int nt = ntypes[n];
            h[n * HID + t] = acc[j] + bb + nemb[nt * HID + t];
        }
    }
}

// ================= GAT projection + attention logits; hp stored bf16 =================
__global__ void gemm_alpha_kernel(const float* __restrict__ h, const float* __restrict__ W,
                                  const float* __restrict__ asrc, const float* __restrict__ adst,
                                  unsigned short* __restrict__ hpb, float* __restrict__ als,
                                  float* __restrict__ ald, int N) {
    int t = threadIdx.x;
    int n0 = blockIdx.x * 8;
    __shared__ float hr[8][HID];
#pragma unroll
    for (int j = 0; j < 8; ++j) {
        int n = n0 + j;
        hr[j][t] = (n < N) ? h[n * HID + t] : 0.f;
    }
    __syncthreads();
    float acc[8] = {0.f};
#pragma unroll 8
    for (int k = 0; k < HID; ++k) {
        float w = W[k * HID + t];
#pragma unroll
        for (int j = 0; j < 8; ++j) acc[j] += hr[j][k] * w;
    }
    float as = asrc[t], ad = adst[t];
#pragma unroll
    for (int j = 0; j < 8; ++j) {
        int n = n0 + j;
        if (n >= N) continue;
        hpb[n * HID + t] = f2bf(acc[j]);
        float ps = acc[j] * as;
        float pd = acc[j] * ad;
#pragma unroll
        for (int m = 8; m >= 1; m >>= 1) {
            ps += __shfl_xor(ps, m, 64);
            pd += __shfl_xor(pd, m, 64);
        }
        if ((t & 15) == 0) {
            int hd = t >> 4;
            als[n * HEADS + hd] = ps;
            ald[n * HEADS + hd] = pd;
        }
    }
}

// ================= fused aggregate: softmax + message sum + bias + LN + residual relu ===========
// one wave per dst; lane owns channels (2*lane, 2*lane+1) -> one head per lane, one ushort2 gather
__global__ void gat_aggregate_kernel(const int* __restrict__ rowptr, const int* __restrict__ esrc,
                                     const float* __restrict__ als, const float* __restrict__ ald,
                                     const ushort2* __restrict__ hpb2, const float* __restrict__ gb,
                                     const float* __restrict__ lg, const float* __restrict__ lb,
                                     float* __restrict__ h, int N) {
    int wave = threadIdx.x >> 6;
    int lane = threadIdx.x & 63;
    int n = blockIdx.x * 4 + wave;
    if (n >= N) return;
    int hd = lane >> 3;                      // head of channels 2*lane, 2*lane+1
    float adv = ald[n * HEADS + hd];
    int row = rowptr[n], end = rowptr[n + 1];   // end > row (self-loop)
    float acc0 = 0.f, acc1 = 0.f, sw = 0.f;
    int src_n = esrc[row];
    ushort2 p_n = hpb2[(size_t)src_n * 64 + lane];
    float ls_n = als[src_n * HEADS + hd];
    for (int i = row; i < end; ++i) {
        ushort2 p = p_n;
        float ls = ls_n;
        if (i + 1 < end) {
            int s2 = esrc[i + 1];
            p_n = hpb2[(size_t)s2 * 64 + lane];
            ls_n = als[s2 * HEADS + hd];
        }
        float l = ls + adv;
        l = l > 0.f ? l : 0.2f * l;
        float w = __expf(l);
        sw += w;
        acc0 += w * bf2f(p.x);
        acc1 += w * bf2f(p.y);
    }
    float inv_sw = 1.f / sw;
    const float2* gb2 = (const float2*)gb;
    const float2* lg2 = (const float2*)lg;
    const float2* lb2 = (const float2*)lb;
    float2 gv = gb2[lane];
    float v0 = acc0 * inv_sw + gv.x;
    float v1 = acc1 * inv_sw + gv.y;
    float sum = v0 + v1;
#pragma unroll
    for (int m = 32; m >= 1; m >>= 1) sum += __shfl_xor(sum, m, 64);
    float mu = sum * (1.f / 128.f);
    float d0 = v0 - mu, d1 = v1 - mu;
    float sq = d0 * d0 + d1 * d1;
#pragma unroll
    for (int m = 32; m >= 1; m >>= 1) sq += __shfl_xor(sq, m, 64);
    float inv = rsqrtf(sq * (1.f / 128.f) + 1e-5f);
    float2 lgv = lg2[lane], lbv = lb2[lane];
    float y0 = d0 * inv * lgv.x + lbv.x;
    float y1 = d1 * inv * lgv.y + lbv.y;
    float2* h2 = (float2*)h;
    float2 hv = h2[(size_t)n * 64 + lane];
    float r0 = y0 + hv.x;
    float r1 = y1 + hv.y;
    h2[(size_t)n * 64 + lane] = make_float2(r0 > 0.f ? r0 : 0.f, r1 > 0.f ? r1 : 0.f);
}

// ================= global attention scores =================
__global__ void score_kernel(const float* __restrict__ h, const float* __restrict__ W1,
                             const float* __restrict__ b1, const float* __restrict__ W2,
                             const float* __restrict__ b2, float* __restrict__ escore, int N) {
    int t = threadIdx.x;
    int n0 = blockIdx.x * 8;
    __shared__ float hr[8][HID];
    __shared__ float part[8][2];
#pragma unroll
    for (int j = 0; j < 8; ++j) {
        int n = n0 + j;
        hr[j][t] = (n < N) ? h[n * HID + t] : 0.f;
    }
    __syncthreads();
    float acc[8];
#pragma unroll
    for (int j = 0; j < 8; ++j) acc[j] = b1[t];
#pragma unroll 8
    for (int k = 0; k < HID; ++k) {
        float w = W1[k * HID + t];
#pragma unroll
        for (int j = 0; j < 8; ++j) acc[j] += hr[j][k] * w;
    }
    float w2 = W2[t];
#pragma unroll
    for (int j = 0; j < 8; ++j) {
        float v = tanhf(acc[j]) * w2;
#pragma unroll
        for (int m = 32; m >= 1; m >>= 1) v += __shfl_xor(v, m, 64);
        if ((t & 63) == 0) part[j][t >> 6] = v;
    }
    __syncthreads();
    if (t < 8) {
        int n = n0 + t;
        if (n < N) escore[n] = expf(part[t][0] + part[t][1] + b2[0]);
    }
}

// ================= per-graph pooling; attention partial atomicAdd'ed into hgZ directly ==========
// 512 threads = 4 node-strided groups of 128 channels.
__global__ void pool_graph_kernel(const float* __restrict__ h, const float* __restrict__ escore,
                                  const int* __restrict__ gstart, float* __restrict__ sums,
                                  float* __restrict__ cnts, float* __restrict__ hgZ, int G) {
    int g = blockIdx.x;
    int t = threadIdx.x;               // 0..511
    int c = t & 127, grp = t >> 7;     // 4 groups
    int s = gstart[g], e = gstart[g + 1];
    float msum = 0.f, asum = 0.f, z = 0.f;
    for (int n = s + grp; n < e; n += 4) {
        float hv = h[(size_t)n * HID + c];
        float es = escore[n];
        msum += hv;
        asum += es * hv;
        if (c == 0) z += es;
    }
    __shared__ float sm[4][HID];
    __shared__ float sa[4][HID];
    __shared__ float sz[4];
    sm[grp][c] = msum;
    sa[grp][c] = asum;
    if (c == 0) sz[grp] = z;
    __syncthreads();
    if (t < HID) {
        float m = sm[0][t] + sm[1][t] + sm[2][t] + sm[3][t];
        float a = sa[0][t] + sa[1][t] + sa[2][t] + sa[3][t];
        sums[(size_t)g * HID + t] = m;
        atomicAdd(&hgZ[t], a);
    } else if (t == HID) {
        cnts[g] = (float)(e - s);
        atomicAdd(&hgZ[HID], sz[0] + sz[1] + sz[2] + sz[3]);
    }
}

// ================= classifier head =================
__global__ void head_kernel(const float* __restrict__ hgZ, const float* __restrict__ sums,
                            const float* __restrict__ cnts, const float* __restrict__ W1,
                            const float* __restrict__ b1, const float* __restrict__ W2,
                            const float* __restrict__ b2, float* __restrict__ out, int G) {
    int g = blockIdx.x;
    int t = threadIdx.x;
    __shared__ float hr[HID];
    __shared__ float part[2];
    float Z = hgZ[HID];
    float cnt = cnts[g];
    cnt = cnt > 1.f ? cnt : 1.f;
    hr[t] = hgZ[t] / Z + sums[(size_t)g * HID + t] / cnt;
    __syncthreads();
    float acc = b1[t];
#pragma unroll 8
    for (int k = 0; k < HID; ++k) acc += hr[k] * W1[k * HID + t];
    acc = acc > 0.f ? acc : 0.f;
    float v = acc * W2[t];
#pragma unroll
    for (int m = 32; m >= 1; m >>= 1) v += __shfl_xor(v, m, 64);
    if ((t & 63) == 0) part[t >> 6] = v;
    __syncthreads();
    if (t == 0) out[g] = part[0] + part[1] + b2[0];
}

extern "C" void kernel_launch(void* const* d_in, const int* in_sizes, int n_in,
                              void* d_out, int out_size, void* d_ws, size_t ws_size,
                              hipStream_t stream) {
    const float* x        = (const float*)d_in[0];
    const int*   ei       = (const int*)d_in[1];
    const int*   ntypes   = (const int*)d_in[2];
    const int*   batch    = (const int*)d_in[3];
    const float* emb_W    = (const float*)d_in[4];
    const float* emb_b    = (const float*)d_in[5];
    const float* nemb     = (const float*)d_in[6];
    const float* gat_W    = (const float*)d_in[7];
    const float* att_src  = (const float*)d_in[8];
    const float* att_dst  = (const float*)d_in[9];
    const float* gat_b    = (const float*)d_in[10];
    const float* ln_g     = (const float*)d_in[11];
    const float* ln_b     = (const float*)d_in[12];
    const float* ga_W1    = (const float*)d_in[13];
    const float* ga_b1    = (const float*)d_in[14];
    const float* ga_W2    = (const float*)d_in[15];
    const float* ga_b2    = (const float*)d_in[16];
    const float* cls_W1   = (const float*)d_in[17];
    const float* cls_b1   = (const float*)d_in[18];
    const float* cls_W2   = (const float*)d_in[19];
    const float* cls_b2   = (const float*)d_in[20];
    float* out = (float*)d_out;

    const int N  = in_sizes[2];
    const int E  = in_sizes[1] / 2;
    const int EE = E + N;
    const int G  = out_size;
    const int NB = (N + 255) / 256;

    float* ws      = (float*)d_ws;
    float* h       = ws;                               // N*128 f32
    float* als     = h + (size_t)N * HID;              // N*8
    float* ald     = als + (size_t)N * HEADS;          // N*8
    float* escore  = ald + (size_t)N * HEADS;          // N
    float* sums    = escore + N;                       // G*128
    float* cnts    = sums + (size_t)G * HID;           // G
    float* hgZ     = cnts + G;                         // 129
    unsigned short* hpb = (unsigned short*)(hgZ + HID + 1);  // N*128 bf16
    int*   rowptr  = (int*)(hpb + (size_t)N * HID);    // N+1
    int*   woff    = rowptr + (N + 1);                 // N
    int*   deg     = woff + N;                         // N
    int*   esrc    = deg + N;                          // EE
    int*   partials= esrc + EE;                        // NB
    int*   gstart  = partials + NB;                    // G+1

    // ---- CSR build ----
    hipMemsetAsync(deg, 0, (size_t)N * sizeof(int), stream);
    hipMemsetAsync(hgZ, 0, (HID + 1) * sizeof(float), stream);
    count_kernel<<<(EE + 255) / 256, 256, 0, stream>>>(ei, deg, E, EE);
    block_sum_kernel<<<NB, 256, 0, stream>>>(deg, partials, N);
    scan_partials_kernel<<<1, 64, 0, stream>>>(partials, NB);
    rowptr_kernel<<<NB, 256, 0, stream>>>(deg, partials, rowptr, woff, N, EE);
    scatter_kernel<<<(EE + 255) / 256, 256, 0, stream>>>(ei, woff, esrc, E, EE);
    gstart_kernel<<<(G + 64) / 64, 64, 0, stream>>>(batch, gstart, N, G);

    // ---- network ----
    embed_kernel<<<(N + 7) / 8, 128, 0, stream>>>(x, emb_W, emb_b, nemb, ntypes, h, N);

    for (int l = 0; l < 3; ++l) {
        gemm_alpha_kernel<<<(N + 7) / 8, 128, 0, stream>>>(
            h, gat_W + (size_t)l * HID * HID, att_src + l * HID, att_dst + l * HID,
            hpb, als, ald, N);
        gat_aggregate_kernel<<<(N + 3) / 4, 256, 0, stream>>>(
            rowptr, esrc, als, ald, (const ushort2*)hpb,
            gat_b + l * HID, ln_g + l * HID, ln_b + l * HID, h, N);
    }

    score_kernel<<<(N + 7) / 8, 128, 0, stream>>>(h, ga_W1, ga_b1, ga_W2, ga_b2, escore, N);
    pool_graph_kernel<<<G, 512, 0, stream>>>(h, escore, gstart, sums, cnts, hgZ, G);
    head_kernel<<<G, 128, 0, stream>>>(hgZ, sums, cnts, cls_W1, cls_b1, cls_W2, cls_b2, out, G);
}

// Round 5
// 574.363 us; speedup vs baseline: 1.3046x; 1.1629x over previous
//
#include <hip/hip_runtime.h>
#include <hip/hip_bf16.h>
#include <math.h>

#define HID 128
#define HEADS 8
#define INDIM 64

__device__ __forceinline__ unsigned short f2bf(float v) {
    unsigned u = __float_as_uint(v);
    u += 0x7FFFu + ((u >> 16) & 1u);   // RNE
    return (unsigned short)(u >> 16);
}
__device__ __forceinline__ float bf2f(unsigned short b) {
    return __uint_as_float(((unsigned)b) << 16);
}
__device__ __forceinline__ float fast_tanh(float x) {
    return 1.f - 2.f / (__expf(2.f * x) + 1.f);
}

// ================= CSR build (by dst) =================

__global__ void count_kernel(const int* __restrict__ ei, int* __restrict__ deg, int E, int EE) {
    int e = blockIdx.x * blockDim.x + threadIdx.x;
    if (e >= EE) return;
    int dst = (e < E) ? ei[E + e] : (e - E);
    atomicAdd(&deg[dst], 1);
}

__global__ void block_sum_kernel(const int* __restrict__ deg, int* __restrict__ partials, int N) {
    __shared__ int sdata[4];
    int t = threadIdx.x;
    int i = blockIdx.x * 256 + t;
    int v = (i < N) ? deg[i] : 0;
#pragma unroll
    for (int m = 32; m >= 1; m >>= 1) v += __shfl_xor(v, m, 64);
    if ((t & 63) == 0) sdata[t >> 6] = v;
    __syncthreads();
    if (t == 0) partials[blockIdx.x] = sdata[0] + sdata[1] + sdata[2] + sdata[3];
}

__global__ void scan_partials_kernel(int* __restrict__ partials, int nb) {
    int lane = threadIdx.x;  // 64 threads
    int carry = 0;
    for (int base = 0; base < nb; base += 64) {
        int i = base + lane;
        int v = (i < nb) ? partials[i] : 0;
        int orig = v;
#pragma unroll
        for (int off = 1; off < 64; off <<= 1) {
            int x = __shfl_up(v, off, 64);
            if (lane >= off) v += x;
        }
        if (i < nb) partials[i] = v - orig + carry;
        carry += __shfl(v, 63, 64);
    }
}

__global__ void rowptr_kernel(const int* __restrict__ deg, const int* __restrict__ partials,
                              int* __restrict__ rowptr, int* __restrict__ woff, int N, int EE) {
    __shared__ int tmp[256];
    int t = threadIdx.x;
    int i = blockIdx.x * 256 + t;
    int v = (i < N) ? deg[i] : 0;
    tmp[t] = v;
    __syncthreads();
#pragma unroll
    for (int off = 1; off < 256; off <<= 1) {
        int x = (t >= off) ? tmp[t - off] : 0;
        __syncthreads();
        tmp[t] += x;
        __syncthreads();
    }
    int excl = tmp[t] - v + partials[blockIdx.x];
    if (i < N) { rowptr[i] = excl; woff[i] = excl; }
    if (blockIdx.x == 0 && t == 0) rowptr[N] = EE;
}

__global__ void scatter_kernel(const int* __restrict__ ei, int* __restrict__ woff,
                               int* __restrict__ esrc, int E, int EE) {
    int e = blockIdx.x * blockDim.x + threadIdx.x;
    if (e >= EE) return;
    int src, dst;
    if (e < E) { src = ei[e]; dst = ei[E + e]; } else { src = dst = e - E; }
    int slot = atomicAdd(&woff[dst], 1);
    esrc[slot] = src;
}

__global__ void gstart_kernel(const int* __restrict__ batch, int* __restrict__ gstart,
                              int N, int G) {
    int g = blockIdx.x * blockDim.x + threadIdx.x;
    if (g > G) return;
    int lo = 0, hi = N;
    while (lo < hi) {
        int mid = (lo + hi) >> 1;
        if (batch[mid] < g) lo = mid + 1; else hi = mid;
    }
    gstart[g] = lo;
}

// ================= embed: 16 nodes/block =================
__global__ void embed_kernel(const float* __restrict__ x, const float* __restrict__ W,
                             const float* __restrict__ b, const float* __restrict__ nemb,
                             const int* __restrict__ ntypes, float* __restrict__ h, int N) {
    int t = threadIdx.x;                 // 0..127
    int n0 = blockIdx.x * 16;
    __shared__ float xr[16 * INDIM];     // 4 KB
    const float4* xg = (const float4*)(x + (size_t)n0 * INDIM);
    float4* xrv = (float4*)xr;
    int limit = (N - n0 < 16 ? N - n0 : 16) * (INDIM / 4);
    for (int i = t; i < 16 * INDIM / 4; i += 128)
        xrv[i] = (i < limit) ? xg[i] : make_float4(0.f, 0.f, 0.f, 0.f);
    __syncthreads();
    const float4* xr4 = (const float4*)xr;   // [16][16]
    float acc[16];
#pragma unroll
    for (int j = 0; j < 16; ++j) acc[j] = 0.f;
    for (int k4 = 0; k4 < INDIM / 4; ++k4) {
        float w0 = W[(4 * k4 + 0) * HID + t];
        float w1 = W[(4 * k4 + 1) * HID + t];
        float w2 = W[(4 * k4 + 2) * HID + t];
        float w3 = W[(4 * k4 + 3) * HID + t];
#pragma unroll
        for (int j = 0; j < 16; ++j) {
            float4 hv = xr4[j * (INDIM / 4) + k4];
            acc[j] += hv.x * w0 + hv.y * w1 + hv.z * w2 + hv.w * w3;
        }
    }
    float bb = b[t];
#pragma unroll
    for (int j = 0; j < 16; ++j) {
        int n = n0 + j;
        if (n < N) {
            int nt = ntypes[n];
            h[(size_t)n * HID + t] = acc[j] + bb + nemb[nt * HID + t];
        }
    }
}

// ================= GAT projection + attention logits (16 nodes/block); hp stored bf16 ==========
__global__ void gemm_alpha_kernel(const float* __restrict__ h, const float* __restrict__ W,
                                  const float* __restrict__ asrc, const float* __restrict__ adst,
                                  unsigned short* __restrict__ hpb, float* __restrict__ als,
                                  float* __restrict__ ald, int N) {
    int t = threadIdx.x;
    int n0 = blockIdx.x * 16;
    __shared__ float hr[16 * HID];       // 8 KB
    const float4* hg = (const float4*)(h + (size_t)n0 * HID);
    float4* hrv = (float4*)hr;
    int limit = (N - n0 < 16 ? N - n0 : 16) * (HID / 4);
    for (int i = t; i < 16 * HID / 4; i += 128)
        hrv[i] = (i < limit) ? hg[i] : make_float4(0.f, 0.f, 0.f, 0.f);
    __syncthreads();
    const float4* hr4 = (const float4*)hr;   // [16][32]
    float acc[16];
#pragma unroll
    for (int j = 0; j < 16; ++j) acc[j] = 0.f;
    for (int k4 = 0; k4 < HID / 4; ++k4) {
        float w0 = W[(4 * k4 + 0) * HID + t];
        float w1 = W[(4 * k4 + 1) * HID + t];
        float w2 = W[(4 * k4 + 2) * HID + t];
        float w3 = W[(4 * k4 + 3) * HID + t];
#pragma unroll
        for (int j = 0; j < 16; ++j) {
            float4 hv = hr4[j * (HID / 4) + k4];
            acc[j] += hv.x * w0 + hv.y * w1 + hv.z * w2 + hv.w * w3;
        }
    }
    float as = asrc[t], ad = adst[t];
#pragma unroll
    for (int j = 0; j < 16; ++j) {
        int n = n0 + j;
        if (n >= N) continue;
        hpb[(size_t)n * HID + t] = f2bf(acc[j]);
        float ps = acc[j] * as;
        float pd = acc[j] * ad;
#pragma unroll
        for (int m = 8; m >= 1; m >>= 1) {
            ps += __shfl_xor(ps, m, 64);
            pd += __shfl_xor(pd, m, 64);
        }
        if ((t & 15) == 0) {
            int hd = t >> 4;
            als[n * HEADS + hd] = ps;
            ald[n * HEADS + hd] = pd;
        }
    }
}

// ================= fused aggregate: 4-wide pipelined edge loop =================
// one wave per dst; lane owns channels (2*lane, 2*lane+1) -> one head per lane
__global__ void gat_aggregate_kernel(const int* __restrict__ rowptr, const int* __restrict__ esrc,
                                     const float* __restrict__ als, const float* __restrict__ ald,
                                     const ushort2* __restrict__ hpb2, const float* __restrict__ gb,
                                     const float* __restrict__ lg, const float* __restrict__ lb,
                                     float* __restrict__ h, int N) {
    int wave = threadIdx.x >> 6;
    int lane = threadIdx.x & 63;
    int n = blockIdx.x * 4 + wave;
    if (n >= N) return;
    int hd = lane >> 3;
    float adv = ald[n * HEADS + hd];
    int row = rowptr[n], end = rowptr[n + 1];   // end > row (self-loop)
    float acc0 = 0.f, acc1 = 0.f, sw = 0.f;
    int last = end - 1;
    for (int i = row; i < end; i += 4) {
        int iB = i + 1 <= last ? i + 1 : last;
        int iC = i + 2 <= last ? i + 2 : last;
        int iD = i + 3 <= last ? i + 3 : last;
        int sA = esrc[i], sB = esrc[iB], sC = esrc[iC], sD = esrc[iD];
        ushort2 pA = hpb2[(size_t)sA * 64 + lane];
        ushort2 pB = hpb2[(size_t)sB * 64 + lane];
        ushort2 pC = hpb2[(size_t)sC * 64 + lane];
        ushort2 pD = hpb2[(size_t)sD * 64 + lane];
        float aA = als[sA * HEADS + hd];
        float aB = als[sB * HEADS + hd];
        float aC = als[sC * HEADS + hd];
        float aD = als[sD * HEADS + hd];
        float mB = (i + 1 < end) ? 1.f : 0.f;
        float mC = (i + 2 < end) ? 1.f : 0.f;
        float mD = (i + 3 < end) ? 1.f : 0.f;
        float lA = aA + adv; lA = lA > 0.f ? lA : 0.2f * lA;
        float lB = aB + adv; lB = lB > 0.f ? lB : 0.2f * lB;
        float lC = aC + adv; lC = lC > 0.f ? lC : 0.2f * lC;
        float lD = aD + adv; lD = lD > 0.f ? lD : 0.2f * lD;
        float wA = __expf(lA);
        float wB = __expf(lB) * mB;
        float wC = __expf(lC) * mC;
        float wD = __expf(lD) * mD;
        sw += (wA + wB) + (wC + wD);
        acc0 += wA * bf2f(pA.x) + wB * bf2f(pB.x) + wC * bf2f(pC.x) + wD * bf2f(pD.x);
        acc1 += wA * bf2f(pA.y) + wB * bf2f(pB.y) + wC * bf2f(pC.y) + wD * bf2f(pD.y);
    }
    float inv_sw = 1.f / sw;
    const float2* gb2 = (const float2*)gb;
    const float2* lg2 = (const float2*)lg;
    const float2* lb2 = (const float2*)lb;
    float2 gv = gb2[lane];
    float v0 = acc0 * inv_sw + gv.x;
    float v1 = acc1 * inv_sw + gv.y;
    float sum = v0 + v1;
#pragma unroll
    for (int m = 32; m >= 1; m >>= 1) sum += __shfl_xor(sum, m, 64);
    float mu = sum * (1.f / 128.f);
    float d0 = v0 - mu, d1 = v1 - mu;
    float sq = d0 * d0 + d1 * d1;
#pragma unroll
    for (int m = 32; m >= 1; m >>= 1) sq += __shfl_xor(sq, m, 64);
    float inv = rsqrtf(sq * (1.f / 128.f) + 1e-5f);
    float2 lgv = lg2[lane], lbv = lb2[lane];
    float y0 = d0 * inv * lgv.x + lbv.x;
    float y1 = d1 * inv * lgv.y + lbv.y;
    float2* h2 = (float2*)h;
    float2 hv = h2[(size_t)n * 64 + lane];
    float r0 = y0 + hv.x;
    float r1 = y1 + hv.y;
    h2[(size_t)n * 64 + lane] = make_float2(r0 > 0.f ? r0 : 0.f, r1 > 0.f ? r1 : 0.f);
}

// ================= global attention scores (16 nodes/block, fast tanh) =================
__global__ void score_kernel(const float* __restrict__ h, const float* __restrict__ W1,
                             const float* __restrict__ b1, const float* __restrict__ W2,
                             const float* __restrict__ b2, float* __restrict__ escore, int N) {
    int t = threadIdx.x;
    int n0 = blockIdx.x * 16;
    __shared__ float hr[16 * HID];
    __shared__ float part[16][2];
    const float4* hg = (const float4*)(h + (size_t)n0 * HID);
    float4* hrv = (float4*)hr;
    int limit = (N - n0 < 16 ? N - n0 : 16) * (HID / 4);
    for (int i = t; i < 16 * HID / 4; i += 128)
        hrv[i] = (i < limit) ? hg[i] : make_float4(0.f, 0.f, 0.f, 0.f);
    __syncthreads();
    const float4* hr4 = (const float4*)hr;
    float acc[16];
    float bb = b1[t];
#pragma unroll
    for (int j = 0; j < 16; ++j) acc[j] = bb;
    for (int k4 = 0; k4 < HID / 4; ++k4) {
        float w0 = W1[(4 * k4 + 0) * HID + t];
        float w1 = W1[(4 * k4 + 1) * HID + t];
        float w2 = W1[(4 * k4 + 2) * HID + t];
        float w3 = W1[(4 * k4 + 3) * HID + t];
#pragma unroll
        for (int j = 0; j < 16; ++j) {
            float4 hv = hr4[j * (HID / 4) + k4];
            acc[j] += hv.x * w0 + hv.y * w1 + hv.z * w2 + hv.w * w3;
        }
    }
    float w2v = W2[t];
#pragma unroll
    for (int j = 0; j < 16; ++j) {
        float v = fast_tanh(acc[j]) * w2v;
#pragma unroll
        for (int m = 32; m >= 1; m >>= 1) v += __shfl_xor(v, m, 64);
        if ((t & 63) == 0) part[j][t >> 6] = v;
    }
    __syncthreads();
    if (t < 16) {
        int n = n0 + t;
        if (n < N) escore[n] = __expf(part[t][0] + part[t][1] + b2[0]);
    }
}

// ================= per-graph pooling =================
__global__ void pool_graph_kernel(const float* __restrict__ h, const float* __restrict__ escore,
                                  const int* __restrict__ gstart, float* __restrict__ sums,
                                  float* __restrict__ cnts, float* __restrict__ hgZ, int G) {
    int g = blockIdx.x;
    int t = threadIdx.x;               // 0..511
    int c = t & 127, grp = t >> 7;     // 4 groups
    int s = gstart[g], e = gstart[g + 1];
    float msum = 0.f, asum = 0.f, z = 0.f;
    for (int n = s + grp; n < e; n += 4) {
        float hv = h[(size_t)n * HID + c];
        float es = escore[n];
        msum += hv;
        asum += es * hv;
        if (c == 0) z += es;
    }
    __shared__ float sm[4][HID];
    __shared__ float sa[4][HID];
    __shared__ float sz[4];
    sm[grp][c] = msum;
    sa[grp][c] = asum;
    if (c == 0) sz[grp] = z;
    __syncthreads();
    if (t < HID) {
        float m = sm[0][t] + sm[1][t] + sm[2][t] + sm[3][t];
        float a = sa[0][t] + sa[1][t] + sa[2][t] + sa[3][t];
        sums[(size_t)g * HID + t] = m;
        atomicAdd(&hgZ[t], a);
    } else if (t == HID) {
        cnts[g] = (float)(e - s);
        atomicAdd(&hgZ[HID], sz[0] + sz[1] + sz[2] + sz[3]);
    }
}

// ================= classifier head =================
__global__ void head_kernel(const float* __restrict__ hgZ, const float* __restrict__ sums,
                            const float* __restrict__ cnts, const float* __restrict__ W1,
                            const float* __restrict__ b1, const float* __restrict__ W2,
                            const float* __restrict__ b2, float* __restrict__ out, int G) {
    int g = blockIdx.x;
    int t = threadIdx.x;
    __shared__ float hr[HID];
    __shared__ float part[2];
    float Z = hgZ[HID];
    float cnt = cnts[g];
    cnt = cnt > 1.f ? cnt : 1.f;
    hr[t] = hgZ[t] / Z + sums[(size_t)g * HID + t] / cnt;
    __syncthreads();
    float acc = b1[t];
#pragma unroll 8
    for (int k = 0; k < HID; ++k) acc += hr[k] * W1[k * HID + t];
    acc = acc > 0.f ? acc : 0.f;
    float v = acc * W2[t];
#pragma unroll
    for (int m = 32; m >= 1; m >>= 1) v += __shfl_xor(v, m, 64);
    if ((t & 63) == 0) part[t >> 6] = v;
    __syncthreads();
    if (t == 0) out[g] = part[0] + part[1] + b2[0];
}

extern "C" void kernel_launch(void* const* d_in, const int* in_sizes, int n_in,
                              void* d_out, int out_size, void* d_ws, size_t ws_size,
                              hipStream_t stream) {
    const float* x        = (const float*)d_in[0];
    const int*   ei       = (const int*)d_in[1];
    const int*   ntypes   = (const int*)d_in[2];
    const int*   batch    = (const int*)d_in[3];
    const float* emb_W    = (const float*)d_in[4];
    const float* emb_b    = (const float*)d_in[5];
    const float* nemb     = (const float*)d_in[6];
    const float* gat_W    = (const float*)d_in[7];
    const float* att_src  = (const float*)d_in[8];
    const float* att_dst  = (const float*)d_in[9];
    const float* gat_b    = (const float*)d_in[10];
    const float* ln_g     = (const float*)d_in[11];
    const float* ln_b     = (const float*)d_in[12];
    const float* ga_W1    = (const float*)d_in[13];
    const float* ga_b1    = (const float*)d_in[14];
    const float* ga_W2    = (const float*)d_in[15];
    const float* ga_b2    = (const float*)d_in[16];
    const float* cls_W1   = (const float*)d_in[17];
    const float* cls_b1   = (const float*)d_in[18];
    const float* cls_W2   = (const float*)d_in[19];
    const float* cls_b2   = (const float*)d_in[20];
    float* out = (float*)d_out;

    const int N  = in_sizes[2];
    const int E  = in_sizes[1] / 2;
    const int EE = E + N;
    const int G  = out_size;
    const int NB = (N + 255) / 256;

    float* ws      = (float*)d_ws;
    float* h       = ws;                               // N*128 f32
    float* als     = h + (size_t)N * HID;              // N*8
    float* ald     = als + (size_t)N * HEADS;          // N*8
    float* escore  = ald + (size_t)N * HEADS;          // N
    float* sums    = escore + N;                       // G*128
    float* cnts    = sums + (size_t)G * HID;           // G
    float* hgZ     = cnts + G;                         // 129
    unsigned short* hpb = (unsigned short*)(hgZ + HID + 1);  // N*128 bf16
    int*   rowptr  = (int*)(hpb + (size_t)N * HID);    // N+1
    int*   woff    = rowptr + (N + 1);                 // N
    int*   deg     = woff + N;                         // N
    int*   esrc    = deg + N;                          // EE
    int*   partials= esrc + EE;                        // NB
    int*   gstart  = partials + NB;                    // G+1

    // ---- CSR build ----
    hipMemsetAsync(deg, 0, (size_t)N * sizeof(int), stream);
    hipMemsetAsync(hgZ, 0, (HID + 1) * sizeof(float), stream);
    count_kernel<<<(EE + 255) / 256, 256, 0, stream>>>(ei, deg, E, EE);
    block_sum_kernel<<<NB, 256, 0, stream>>>(deg, partials, N);
    scan_partials_kernel<<<1, 64, 0, stream>>>(partials, NB);
    rowptr_kernel<<<NB, 256, 0, stream>>>(deg, partials, rowptr, woff, N, EE);
    scatter_kernel<<<(EE + 255) / 256, 256, 0, stream>>>(ei, woff, esrc, E, EE);
    gstart_kernel<<<(G + 64) / 64, 64, 0, stream>>>(batch, gstart, N, G);

    // ---- network ----
    embed_kernel<<<(N + 15) / 16, 128, 0, stream>>>(x, emb_W, emb_b, nemb, ntypes, h, N);

    for (int l = 0; l < 3; ++l) {
        gemm_alpha_kernel<<<(N + 15) / 16, 128, 0, stream>>>(
            h, gat_W + (size_t)l * HID * HID, att_src + l * HID, att_dst + l * HID,
            hpb, als, ald, N);
        gat_aggregate_kernel<<<(N + 3) / 4, 256, 0, stream>>>(
            rowptr, esrc, als, ald, (const ushort2*)hpb,
            gat_b + l * HID, ln_g + l * HID, ln_b + l * HID, h, N);
    }

    score_kernel<<<(N + 15) / 16, 128, 0, stream>>>(h, ga_W1, ga_b1, ga_W2, ga_b2, escore, N);
    pool_graph_kernel<<<G, 512, 0, stream>>>(h, escore, gstart, sums, cnts, hgZ, G);
    head_kernel<<<G, 128, 0, stream>>>(hgZ, sums, cnts, cls_W1, cls_b1, cls_W2, cls_b2, out, G);
}

// Round 6
// 487.411 us; speedup vs baseline: 1.5373x; 1.1784x over previous
//
#include <hip/hip_runtime.h>
#include <hip/hip_bf16.h>
#include <math.h>

#define HID 128
#define HEADS 8
#define INDIM 64

typedef _Float16 f16x8 __attribute__((ext_vector_type(8)));
typedef _Float16 f16x4 __attribute__((ext_vector_type(4)));
typedef float f32x4 __attribute__((ext_vector_type(4)));

__device__ __forceinline__ float h2f(unsigned short u) {
    _Float16 h;
    __builtin_memcpy(&h, &u, 2);
    return (float)h;
}
__device__ __forceinline__ float fast_tanh(float x) {
    return 1.f - 2.f / (__expf(2.f * x) + 1.f);
}

// ================= CSR build (by dst) =================

__global__ void count_kernel(const int* __restrict__ ei, int* __restrict__ deg, int E, int EE) {
    int e = blockIdx.x * blockDim.x + threadIdx.x;
    if (e >= EE) return;
    int dst = (e < E) ? ei[E + e] : (e - E);
    atomicAdd(&deg[dst], 1);
}

__global__ void block_sum_kernel(const int* __restrict__ deg, int* __restrict__ partials, int N) {
    __shared__ int sdata[4];
    int t = threadIdx.x;
    int i = blockIdx.x * 256 + t;
    int v = (i < N) ? deg[i] : 0;
#pragma unroll
    for (int m = 32; m >= 1; m >>= 1) v += __shfl_xor(v, m, 64);
    if ((t & 63) == 0) sdata[t >> 6] = v;
    __syncthreads();
    if (t == 0) partials[blockIdx.x] = sdata[0] + sdata[1] + sdata[2] + sdata[3];
}

__global__ void scan_partials_kernel(int* __restrict__ partials, int nb) {
    int lane = threadIdx.x;  // 64 threads
    int carry = 0;
    for (int base = 0; base < nb; base += 64) {
        int i = base + lane;
        int v = (i < nb) ? partials[i] : 0;
        int orig = v;
#pragma unroll
        for (int off = 1; off < 64; off <<= 1) {
            int x = __shfl_up(v, off, 64);
            if (lane >= off) v += x;
        }
        if (i < nb) partials[i] = v - orig + carry;
        carry += __shfl(v, 63, 64);
    }
}

__global__ void rowptr_kernel(const int* __restrict__ deg, const int* __restrict__ partials,
                              int* __restrict__ rowptr, int* __restrict__ woff, int N, int EE) {
    __shared__ int tmp[256];
    int t = threadIdx.x;
    int i = blockIdx.x * 256 + t;
    int v = (i < N) ? deg[i] : 0;
    tmp[t] = v;
    __syncthreads();
#pragma unroll
    for (int off = 1; off < 256; off <<= 1) {
        int x = (t >= off) ? tmp[t - off] : 0;
        __syncthreads();
        tmp[t] += x;
        __syncthreads();
    }
    int excl = tmp[t] - v + partials[blockIdx.x];
    if (i < N) { rowptr[i] = excl; woff[i] = excl; }
    if (blockIdx.x == 0 && t == 0) rowptr[N] = EE;
}

__global__ void scatter_kernel(const int* __restrict__ ei, int* __restrict__ woff,
                               int* __restrict__ esrc, int E, int EE) {
    int e = blockIdx.x * blockDim.x + threadIdx.x;
    if (e >= EE) return;
    int src, dst;
    if (e < E) { src = ei[e]; dst = ei[E + e]; } else { src = dst = e - E; }
    int slot = atomicAdd(&woff[dst], 1);
    esrc[slot] = src;
}

__global__ void gstart_kernel(const int* __restrict__ batch, int* __restrict__ gstart,
                              int N, int G) {
    int g = blockIdx.x * blockDim.x + threadIdx.x;
    if (g > G) return;
    int lo = 0, hi = N;
    while (lo < hi) {
        int mid = (lo + hi) >> 1;
        if (batch[mid] < g) lo = mid + 1; else hi = mid;
    }
    gstart[g] = lo;
}

// ================= weight convert: W[K][128] fp32 -> Wt[128][K] f16 =================
__global__ void convert_wt_kernel(const float* __restrict__ W, _Float16* __restrict__ Wt, int K) {
    int idx = blockIdx.x * blockDim.x + threadIdx.x;
    if (idx >= K * 128) return;
    int k = idx >> 7, n = idx & 127;
    Wt[n * K + k] = (_Float16)W[idx];
}

// ================= unified MFMA projection kernel =================
// C[64 x 128] = A[64 x K] @ W[K x 128], f16 inputs, fp32 accum.
// mode 0: embed epilogue (bias + ntype_emb -> hout fp32)
// mode 1: GAT proj epilogue (als/ald logits + hp f16 store)
// mode 2: score epilogue (tanh MLP -> escore)
__global__ __launch_bounds__(256) void mfma_proj_kernel(
    int mode, int K, int N,
    const float* __restrict__ A, const _Float16* __restrict__ Wt,
    const float* __restrict__ bias, const float* __restrict__ nemb,
    const int* __restrict__ ntypes, float* __restrict__ hout,
    const float* __restrict__ asrc, const float* __restrict__ adst,
    unsigned* __restrict__ hp_out, float* __restrict__ als, float* __restrict__ ald,
    const float* __restrict__ w2, const float* __restrict__ b2,
    float* __restrict__ escore)
{
    __shared__ _Float16 a_lds[64 * 136];   // rows padded +8 f16 (16B) to break bank aliasing
    __shared__ _Float16 w_lds[128 * 136];
    int t = threadIdx.x;
    int n0 = blockIdx.x * 64;

    // ---- stage A (fp32 -> f16) ----
    int K4 = K >> 2;
    for (int i = t; i < 64 * K4; i += 256) {
        int row = i / K4, c4 = i - row * K4;
        float4 v = make_float4(0.f, 0.f, 0.f, 0.f);
        if (n0 + row < N) v = *(const float4*)&A[(size_t)(n0 + row) * K + 4 * c4];
        f16x4 o;
        o[0] = (_Float16)v.x; o[1] = (_Float16)v.y; o[2] = (_Float16)v.z; o[3] = (_Float16)v.w;
        *(f16x4*)&a_lds[row * 136 + 4 * c4] = o;
    }
    // ---- stage Wt ----
    int K8 = K >> 3;
    for (int i = t; i < 128 * K8; i += 256) {
        int row = i / K8, c8 = i - row * K8;
        *(f16x8*)&w_lds[row * 136 + 8 * c8] = *(const f16x8*)&Wt[(size_t)row * K + 8 * c8];
    }
    __syncthreads();

    int lane = t & 63, wv = t >> 6;
    int l15 = lane & 15, quad = lane >> 4;

    f32x4 acc[8];
#pragma unroll
    for (int c = 0; c < 8; ++c) acc[c] = (f32x4){0.f, 0.f, 0.f, 0.f};

    int ksteps = K >> 5;
    for (int kk = 0; kk < ksteps; ++kk) {
        f16x8 af = *(const f16x8*)&a_lds[(wv * 16 + l15) * 136 + kk * 32 + quad * 8];
#pragma unroll
        for (int c = 0; c < 8; ++c) {
            f16x8 bf = *(const f16x8*)&w_lds[(c * 16 + l15) * 136 + kk * 32 + quad * 8];
            acc[c] = __builtin_amdgcn_mfma_f32_16x16x32_f16(af, bf, acc[c], 0, 0, 0);
        }
    }

    // C layout: row = wv*16 + quad*4 + r, col = c*16 + l15  (m89-verified)
    if (mode == 0) {
        float bv[8];
#pragma unroll
        for (int c = 0; c < 8; ++c) bv[c] = bias[c * 16 + l15];
#pragma unroll
        for (int r = 0; r < 4; ++r) {
            int n = n0 + wv * 16 + quad * 4 + r;
            if (n >= N) continue;
            int nt = ntypes[n];
#pragma unroll
            for (int c = 0; c < 8; ++c)
                hout[(size_t)n * HID + c * 16 + l15] = acc[c][r] + bv[c] + nemb[nt * HID + c * 16 + l15];
        }
    } else if (mode == 1) {
        // attention logits: col-tile c IS head c
#pragma unroll
        for (int c = 0; c < 8; ++c) {
            float asv = asrc[c * 16 + l15];
            float adv = adst[c * 16 + l15];
#pragma unroll
            for (int r = 0; r < 4; ++r) {
                float va = acc[c][r] * asv;
                float vd = acc[c][r] * adv;
#pragma unroll
                for (int m = 8; m >= 1; m >>= 1) {
                    va += __shfl_xor(va, m, 64);
                    vd += __shfl_xor(vd, m, 64);
                }
                if (l15 == 0) {
                    int n = n0 + wv * 16 + quad * 4 + r;
                    if (n < N) {
                        als[n * HEADS + c] = va;
                        ald[n * HEADS + c] = vd;
                    }
                }
            }
        }
        // hp f16 store via LDS repack (coalesced 4B stores)
        __syncthreads();
#pragma unroll
        for (int c = 0; c < 8; ++c)
#pragma unroll
            for (int r = 0; r < 4; ++r)
                a_lds[(wv * 16 + quad * 4 + r) * 136 + c * 16 + l15] = (_Float16)acc[c][r];
        __syncthreads();
        for (int i = t; i < 64 * 64; i += 256) {
            int row = i >> 6, c2 = i & 63;
            int n = n0 + row;
            if (n < N) hp_out[(size_t)n * 64 + c2] = *(const unsigned*)&a_lds[row * 136 + 2 * c2];
        }
    } else {
        // score: per-row sum_c tanh(acc + b1)*W2 -> exp(. + b2)
        float b2v = b2[0];
        float treg[4] = {0.f, 0.f, 0.f, 0.f};
#pragma unroll
        for (int c = 0; c < 8; ++c) {
            float b1v = bias[c * 16 + l15];
            float w2v = w2[c * 16 + l15];
#pragma unroll
            for (int r = 0; r < 4; ++r)
                treg[r] += fast_tanh(acc[c][r] + b1v) * w2v;
        }
#pragma unroll
        for (int r = 0; r < 4; ++r) {
            float v = treg[r];
#pragma unroll
            for (int m = 8; m >= 1; m >>= 1) v += __shfl_xor(v, m, 64);
            if (l15 == 0) {
                int n = n0 + wv * 16 + quad * 4 + r;
                if (n < N) escore[n] = __expf(v + b2v);
            }
        }
    }
}

// ================= fused aggregate: 4-wide pipelined edge loop (hp is f16) =================
__global__ void gat_aggregate_kernel(const int* __restrict__ rowptr, const int* __restrict__ esrc,
                                     const float* __restrict__ als, const float* __restrict__ ald,
                                     const ushort2* __restrict__ hpb2, const float* __restrict__ gb,
                                     const float* __restrict__ lg, const float* __restrict__ lb,
                                     float* __restrict__ h, int N) {
    int wave = threadIdx.x >> 6;
    int lane = threadIdx.x & 63;
    int n = blockIdx.x * 4 + wave;
    if (n >= N) return;
    int hd = lane >> 3;
    float adv = ald[n * HEADS + hd];
    int row = rowptr[n], end = rowptr[n + 1];   // end > row (self-loop)
    float acc0 = 0.f, acc1 = 0.f, sw = 0.f;
    int last = end - 1;
    for (int i = row; i < end; i += 4) {
        int iB = i + 1 <= last ? i + 1 : last;
        int iC = i + 2 <= last ? i + 2 : last;
        int iD = i + 3 <= last ? i + 3 : last;
        int sA = esrc[i], sB = esrc[iB], sC = esrc[iC], sD = esrc[iD];
        ushort2 pA = hpb2[(size_t)sA * 64 + lane];
        ushort2 pB = hpb2[(size_t)sB * 64 + lane];
        ushort2 pC = hpb2[(size_t)sC * 64 + lane];
        ushort2 pD = hpb2[(size_t)sD * 64 + lane];
        float aA = als[sA * HEADS + hd];
        float aB = als[sB * HEADS + hd];
        float aC = als[sC * HEADS + hd];
        float aD = als[sD * HEADS + hd];
        float mB = (i + 1 < end) ? 1.f : 0.f;
        float mC = (i + 2 < end) ? 1.f : 0.f;
        float mD = (i + 3 < end) ? 1.f : 0.f;
        float lA = aA + adv; lA = lA > 0.f ? lA : 0.2f * lA;
        float lB = aB + adv; lB = lB > 0.f ? lB : 0.2f * lB;
        float lC = aC + adv; lC = lC > 0.f ? lC : 0.2f * lC;
        float lD = aD + adv; lD = lD > 0.f ? lD : 0.2f * lD;
        float wA = __expf(lA);
        float wB = __expf(lB) * mB;
        float wC = __expf(lC) * mC;
        float wD = __expf(lD) * mD;
        sw += (wA + wB) + (wC + wD);
        acc0 += wA * h2f(pA.x) + wB * h2f(pB.x) + wC * h2f(pC.x) + wD * h2f(pD.x);
        acc1 += wA * h2f(pA.y) + wB * h2f(pB.y) + wC * h2f(pC.y) + wD * h2f(pD.y);
    }
    float inv_sw = 1.f / sw;
    const float2* gb2 = (const float2*)gb;
    const float2* lg2 = (const float2*)lg;
    const float2* lb2 = (const float2*)lb;
    float2 gv = gb2[lane];
    float v0 = acc0 * inv_sw + gv.x;
    float v1 = acc1 * inv_sw + gv.y;
    float sum = v0 + v1;
#pragma unroll
    for (int m = 32; m >= 1; m >>= 1) sum += __shfl_xor(sum, m, 64);
    float mu = sum * (1.f / 128.f);
    float d0 = v0 - mu, d1 = v1 - mu;
    float sq = d0 * d0 + d1 * d1;
#pragma unroll
    for (int m = 32; m >= 1; m >>= 1) sq += __shfl_xor(sq, m, 64);
    float inv = rsqrtf(sq * (1.f / 128.f) + 1e-5f);
    float2 lgv = lg2[lane], lbv = lb2[lane];
    float y0 = d0 * inv * lgv.x + lbv.x;
    float y1 = d1 * inv * lgv.y + lbv.y;
    float2* h2 = (float2*)h;
    float2 hv = h2[(size_t)n * 64 + lane];
    float r0 = y0 + hv.x;
    float r1 = y1 + hv.y;
    h2[(size_t)n * 64 + lane] = make_float2(r0 > 0.f ? r0 : 0.f, r1 > 0.f ? r1 : 0.f);
}

// ================= per-graph pooling =================
__global__ void pool_graph_kernel(const float* __restrict__ h, const float* __restrict__ escore,
                                  const int* __restrict__ gstart, float* __restrict__ sums,
                                  float* __restrict__ cnts, float* __restrict__ hgZ, int G) {
    int g = blockIdx.x;
    int t = threadIdx.x;               // 0..511
    int c = t & 127, grp = t >> 7;     // 4 groups
    int s = gstart[g], e = gstart[g + 1];
    float msum = 0.f, asum = 0.f, z = 0.f;
    for (int n = s + grp; n < e; n += 4) {
        float hv = h[(size_t)n * HID + c];
        float es = escore[n];
        msum += hv;
        asum += es * hv;
        if (c == 0) z += es;
    }
    __shared__ float sm[4][HID];
    __shared__ float sa[4][HID];
    __shared__ float sz[4];
    sm[grp][c] = msum;
    sa[grp][c] = asum;
    if (c == 0) sz[grp] = z;
    __syncthreads();
    if (t < HID) {
        float m = sm[0][t] + sm[1][t] + sm[2][t] + sm[3][t];
        float a = sa[0][t] + sa[1][t] + sa[2][t] + sa[3][t];
        sums[(size_t)g * HID + t] = m;
        atomicAdd(&hgZ[t], a);
    } else if (t == HID) {
        cnts[g] = (float)(e - s);
        atomicAdd(&hgZ[HID], sz[0] + sz[1] + sz[2] + sz[3]);
    }
}

// ================= classifier head =================
__global__ void head_kernel(const float* __restrict__ hgZ, const float* __restrict__ sums,
                            const float* __restrict__ cnts, const float* __restrict__ W1,
                            const float* __restrict__ b1, const float* __restrict__ W2,
                            const float* __restrict__ b2, float* __restrict__ out, int G) {
    int g = blockIdx.x;
    int t = threadIdx.x;
    __shared__ float hr[HID];
    __shared__ float part[2];
    float Z = hgZ[HID];
    float cnt = cnts[g];
    cnt = cnt > 1.f ? cnt : 1.f;
    hr[t] = hgZ[t] / Z + sums[(size_t)g * HID + t] / cnt;
    __syncthreads();
    float acc = b1[t];
#pragma unroll 8
    for (int k = 0; k < HID; ++k) acc += hr[k] * W1[k * HID + t];
    acc = acc > 0.f ? acc : 0.f;
    float v = acc * W2[t];
#pragma unroll
    for (int m = 32; m >= 1; m >>= 1) v += __shfl_xor(v, m, 64);
    if ((t & 63) == 0) part[t >> 6] = v;
    __syncthreads();
    if (t == 0) out[g] = part[0] + part[1] + b2[0];
}

extern "C" void kernel_launch(void* const* d_in, const int* in_sizes, int n_in,
                              void* d_out, int out_size, void* d_ws, size_t ws_size,
                              hipStream_t stream) {
    const float* x        = (const float*)d_in[0];
    const int*   ei       = (const int*)d_in[1];
    const int*   ntypes   = (const int*)d_in[2];
    const int*   batch    = (const int*)d_in[3];
    const float* emb_W    = (const float*)d_in[4];
    const float* emb_b    = (const float*)d_in[5];
    const float* nemb     = (const float*)d_in[6];
    const float* gat_W    = (const float*)d_in[7];
    const float* att_src  = (const float*)d_in[8];
    const float* att_dst  = (const float*)d_in[9];
    const float* gat_b    = (const float*)d_in[10];
    const float* ln_g     = (const float*)d_in[11];
    const float* ln_b     = (const float*)d_in[12];
    const float* ga_W1    = (const float*)d_in[13];
    const float* ga_b1    = (const float*)d_in[14];
    const float* ga_W2    = (const float*)d_in[15];
    const float* ga_b2    = (const float*)d_in[16];
    const float* cls_W1   = (const float*)d_in[17];
    const float* cls_b1   = (const float*)d_in[18];
    const float* cls_W2   = (const float*)d_in[19];
    const float* cls_b2   = (const float*)d_in[20];
    float* out = (float*)d_out;

    const int N  = in_sizes[2];
    const int E  = in_sizes[1] / 2;
    const int EE = E + N;
    const int G  = out_size;
    const int NB = (N + 255) / 256;

    float* ws      = (float*)d_ws;
    float* h       = ws;                               // N*128 f32
    float* als     = h + (size_t)N * HID;              // N*8
    float* ald     = als + (size_t)N * HEADS;          // N*8
    float* escore  = ald + (size_t)N * HEADS;          // N
    float* sums    = escore + N;                       // G*128
    float* cnts    = sums + (size_t)G * HID;           // G
    float* hgZ     = cnts + G;                         // 129
    unsigned short* hpb = (unsigned short*)(hgZ + HID + 1);  // N*128 f16
    int*   rowptr  = (int*)(hpb + (size_t)N * HID);    // N+1
    int*   woff    = rowptr + (N + 1);                 // N
    int*   deg     = woff + N;                         // N
    int*   esrc    = deg + N;                          // EE
    int*   partials= esrc + EE;                        // NB
    int*   gstart  = partials + NB;                    // G+1
    _Float16* wt_emb = (_Float16*)(gstart + G + 1);    // 128*64
    _Float16* wt_gat = wt_emb + 128 * 64;              // 3*128*128
    _Float16* wt_ga1 = wt_gat + 3 * 128 * 128;         // 128*128

    // ---- CSR build + weight converts ----
    hipMemsetAsync(deg, 0, (size_t)N * sizeof(int), stream);
    hipMemsetAsync(hgZ, 0, (HID + 1) * sizeof(float), stream);
    count_kernel<<<(EE + 255) / 256, 256, 0, stream>>>(ei, deg, E, EE);
    block_sum_kernel<<<NB, 256, 0, stream>>>(deg, partials, N);
    scan_partials_kernel<<<1, 64, 0, stream>>>(partials, NB);
    rowptr_kernel<<<NB, 256, 0, stream>>>(deg, partials, rowptr, woff, N, EE);
    scatter_kernel<<<(EE + 255) / 256, 256, 0, stream>>>(ei, woff, esrc, E, EE);
    gstart_kernel<<<(G + 64) / 64, 64, 0, stream>>>(batch, gstart, N, G);

    convert_wt_kernel<<<(64 * 128 + 255) / 256, 256, 0, stream>>>(emb_W, wt_emb, 64);
    for (int l = 0; l < 3; ++l)
        convert_wt_kernel<<<(128 * 128 + 255) / 256, 256, 0, stream>>>(
            gat_W + (size_t)l * HID * HID, wt_gat + (size_t)l * HID * HID, 128);
    convert_wt_kernel<<<(128 * 128 + 255) / 256, 256, 0, stream>>>(ga_W1, wt_ga1, 128);

    const int PB = (N + 63) / 64;

    // ---- network ----
    mfma_proj_kernel<<<PB, 256, 0, stream>>>(
        0, INDIM, N, x, wt_emb, emb_b, nemb, ntypes, h,
        nullptr, nullptr, nullptr, nullptr, nullptr, nullptr, nullptr, nullptr);

    for (int l = 0; l < 3; ++l) {
        mfma_proj_kernel<<<PB, 256, 0, stream>>>(
            1, HID, N, h, wt_gat + (size_t)l * HID * HID,
            nullptr, nullptr, nullptr, nullptr,
            att_src + l * HID, att_dst + l * HID,
            (unsigned*)hpb, als, ald, nullptr, nullptr, nullptr);
        gat_aggregate_kernel<<<(N + 3) / 4, 256, 0, stream>>>(
            rowptr, esrc, als, ald, (const ushort2*)hpb,
            gat_b + l * HID, ln_g + l * HID, ln_b + l * HID, h, N);
    }

    mfma_proj_kernel<<<PB, 256, 0, stream>>>(
        2, HID, N, h, wt_ga1, ga_b1, nullptr, nullptr, nullptr,
        nullptr, nullptr, nullptr, nullptr, nullptr, ga_W2, ga_b2, escore);

    pool_graph_kernel<<<G, 512, 0, stream>>>(h, escore, gstart, sums, cnts, hgZ, G);
    head_kernel<<<G, 128, 0, stream>>>(hgZ, sums, cnts, cls_W1, cls_b1, cls_W2, cls_b2, out, G);
}

// Round 7
// 437.483 us; speedup vs baseline: 1.7128x; 1.1141x over previous
//
#include <hip/hip_runtime.h>
#include <hip/hip_bf16.h>
#include <math.h>

#define HID 128
#define HEADS 8
#define INDIM 64

typedef _Float16 f16x8 __attribute__((ext_vector_type(8)));
typedef _Float16 f16x4 __attribute__((ext_vector_type(4)));
typedef float f32x4 __attribute__((ext_vector_type(4)));

__device__ __forceinline__ float fast_tanh(float x) {
    return 1.f - 2.f / (__expf(2.f * x) + 1.f);
}

// ================= CSR build (by dst) =================

__global__ void count_kernel(const int* __restrict__ ei, int* __restrict__ deg, int E, int EE) {
    int e = blockIdx.x * blockDim.x + threadIdx.x;
    if (e >= EE) return;
    int dst = (e < E) ? ei[E + e] : (e - E);
    atomicAdd(&deg[dst], 1);
}

__global__ void block_sum_kernel(const int* __restrict__ deg, int* __restrict__ partials, int N) {
    __shared__ int sdata[4];
    int t = threadIdx.x;
    int i = blockIdx.x * 256 + t;
    int v = (i < N) ? deg[i] : 0;
#pragma unroll
    for (int m = 32; m >= 1; m >>= 1) v += __shfl_xor(v, m, 64);
    if ((t & 63) == 0) sdata[t >> 6] = v;
    __syncthreads();
    if (t == 0) partials[blockIdx.x] = sdata[0] + sdata[1] + sdata[2] + sdata[3];
}

__global__ void scan_partials_kernel(int* __restrict__ partials, int nb) {
    int lane = threadIdx.x;  // 64 threads
    int carry = 0;
    for (int base = 0; base < nb; base += 64) {
        int i = base + lane;
        int v = (i < nb) ? partials[i] : 0;
        int orig = v;
#pragma unroll
        for (int off = 1; off < 64; off <<= 1) {
            int x = __shfl_up(v, off, 64);
            if (lane >= off) v += x;
        }
        if (i < nb) partials[i] = v - orig + carry;
        carry += __shfl(v, 63, 64);
    }
}

__global__ void rowptr_kernel(const int* __restrict__ deg, const int* __restrict__ partials,
                              int* __restrict__ rowptr, int* __restrict__ woff, int N, int EE) {
    __shared__ int tmp[256];
    int t = threadIdx.x;
    int i = blockIdx.x * 256 + t;
    int v = (i < N) ? deg[i] : 0;
    tmp[t] = v;
    __syncthreads();
#pragma unroll
    for (int off = 1; off < 256; off <<= 1) {
        int x = (t >= off) ? tmp[t - off] : 0;
        __syncthreads();
        tmp[t] += x;
        __syncthreads();
    }
    int excl = tmp[t] - v + partials[blockIdx.x];
    if (i < N) { rowptr[i] = excl; woff[i] = excl; }
    if (blockIdx.x == 0 && t == 0) rowptr[N] = EE;
}

__global__ void scatter_kernel(const int* __restrict__ ei, int* __restrict__ woff,
                               int* __restrict__ esrc, int E, int EE) {
    int e = blockIdx.x * blockDim.x + threadIdx.x;
    if (e >= EE) return;
    int src, dst;
    if (e < E) { src = ei[e]; dst = ei[E + e]; } else { src = dst = e - E; }
    int slot = atomicAdd(&woff[dst], 1);
    esrc[slot] = src;
}

__global__ void gstart_kernel(const int* __restrict__ batch, int* __restrict__ gstart,
                              int N, int G) {
    int g = blockIdx.x * blockDim.x + threadIdx.x;
    if (g > G) return;
    int lo = 0, hi = N;
    while (lo < hi) {
        int mid = (lo + hi) >> 1;
        if (batch[mid] < g) lo = mid + 1; else hi = mid;
    }
    gstart[g] = lo;
}

// ================= converts =================
__global__ void convert_x_kernel(const float* __restrict__ x, _Float16* __restrict__ x16, int tot4) {
    int i = blockIdx.x * blockDim.x + threadIdx.x;
    if (i >= tot4) return;
    float4 v = ((const float4*)x)[i];
    f16x4 o; o[0] = (_Float16)v.x; o[1] = (_Float16)v.y; o[2] = (_Float16)v.z; o[3] = (_Float16)v.w;
    *(f16x4*)&x16[4 * i] = o;
}

// all weights transposed to [n][k] f16 in one launch
__global__ void convert_w_kernel(const float* __restrict__ emb_W, const float* __restrict__ gat_W,
                                 const float* __restrict__ ga_W1, _Float16* __restrict__ wt_emb,
                                 _Float16* __restrict__ wt_gat, _Float16* __restrict__ wt_ga1) {
    int i = blockIdx.x * blockDim.x + threadIdx.x;
    if (i < 8192) {                       // emb_W [64][128]
        int k = i >> 7, n = i & 127;
        wt_emb[n * 64 + k] = (_Float16)emb_W[i];
    } else if (i < 8192 + 49152) {        // gat_W [3][128][128]
        int j = i - 8192;
        int l = j >> 14, r = j & 16383;
        int k = r >> 7, n = r & 127;
        wt_gat[l * 16384 + n * 128 + k] = (_Float16)gat_W[j];
    } else if (i < 73728) {               // ga_W1 [128][128]
        int j = i - 57344;
        int k = j >> 7, n = j & 127;
        wt_ga1[n * 128 + k] = (_Float16)ga_W1[j];
    }
}

// ================= unified MFMA projection kernel =================
// C[64 x 128] = A16[64 x K] @ W[K x 128]; A fragments loaded directly from global f16.
// mode 0: embed epilogue (bias + ntype_emb -> h16)
// mode 1: GAT proj epilogue (als/ald logits + hp16 store)
// mode 2: score epilogue (tanh MLP -> escore)
__global__ __launch_bounds__(256) void mfma_proj_kernel(
    int mode, int K, int N,
    const _Float16* __restrict__ A16, const _Float16* __restrict__ Wt,
    const float* __restrict__ bias, const float* __restrict__ nemb,
    const int* __restrict__ ntypes, _Float16* __restrict__ h16out,
    const float* __restrict__ asrc, const float* __restrict__ adst,
    _Float16* __restrict__ hp_out, float* __restrict__ als, float* __restrict__ ald,
    const float* __restrict__ w2, const float* __restrict__ b2,
    float* __restrict__ escore)
{
    __shared__ _Float16 w_lds[128 * 136];   // 34.8 KB, row pad +8
    int t = threadIdx.x;
    int n0 = blockIdx.x * 64;

    int K8 = K >> 3;
    for (int i = t; i < 128 * K8; i += 256) {
        int row = i / K8, c8 = i - row * K8;
        *(f16x8*)&w_lds[row * 136 + 8 * c8] = *(const f16x8*)&Wt[(size_t)row * K + 8 * c8];
    }
    __syncthreads();

    int lane = t & 63, wv = t >> 6;
    int l15 = lane & 15, quad = lane >> 4;
    int arow = n0 + wv * 16 + l15;
    if (arow > N - 1) arow = N - 1;       // clamp: result rows >= N never stored

    f32x4 acc[8];
#pragma unroll
    for (int c = 0; c < 8; ++c) acc[c] = (f32x4){0.f, 0.f, 0.f, 0.f};

    int ksteps = K >> 5;
    for (int kk = 0; kk < ksteps; ++kk) {
        f16x8 af = *(const f16x8*)&A16[(size_t)arow * K + kk * 32 + quad * 8];
#pragma unroll
        for (int c = 0; c < 8; ++c) {
            f16x8 bf = *(const f16x8*)&w_lds[(c * 16 + l15) * 136 + kk * 32 + quad * 8];
            acc[c] = __builtin_amdgcn_mfma_f32_16x16x32_f16(af, bf, acc[c], 0, 0, 0);
        }
    }

    // C layout: row = wv*16 + quad*4 + r, col = c*16 + l15
    if (mode == 0) {
        float bv[8];
#pragma unroll
        for (int c = 0; c < 8; ++c) bv[c] = bias[c * 16 + l15];
        __syncthreads();
#pragma unroll
        for (int r = 0; r < 4; ++r) {
            int n = n0 + wv * 16 + quad * 4 + r;
            int nt = (n < N) ? ntypes[n] : 0;
#pragma unroll
            for (int c = 0; c < 8; ++c)
                w_lds[(wv * 16 + quad * 4 + r) * 136 + c * 16 + l15] =
                    (_Float16)(acc[c][r] + bv[c] + nemb[nt * HID + c * 16 + l15]);
        }
        __syncthreads();
        for (int i = t; i < 64 * 16; i += 256) {
            int row = i >> 4, c8 = i & 15;
            int n = n0 + row;
            if (n < N) *(f16x8*)&h16out[(size_t)n * HID + 8 * c8] = *(const f16x8*)&w_lds[row * 136 + 8 * c8];
        }
    } else if (mode == 1) {
#pragma unroll
        for (int c = 0; c < 8; ++c) {
            float asv = asrc[c * 16 + l15];
            float adv = adst[c * 16 + l15];
#pragma unroll
            for (int r = 0; r < 4; ++r) {
                float va = acc[c][r] * asv;
                float vd = acc[c][r] * adv;
#pragma unroll
                for (int m = 8; m >= 1; m >>= 1) {
                    va += __shfl_xor(va, m, 64);
                    vd += __shfl_xor(vd, m, 64);
                }
                if (l15 == 0) {
                    int n = n0 + wv * 16 + quad * 4 + r;
                    if (n < N) {
                        als[n * HEADS + c] = va;
                        ald[n * HEADS + c] = vd;
                    }
                }
            }
        }
        __syncthreads();
#pragma unroll
        for (int c = 0; c < 8; ++c)
#pragma unroll
            for (int r = 0; r < 4; ++r)
                w_lds[(wv * 16 + quad * 4 + r) * 136 + c * 16 + l15] = (_Float16)acc[c][r];
        __syncthreads();
        for (int i = t; i < 64 * 16; i += 256) {
            int row = i >> 4, c8 = i & 15;
            int n = n0 + row;
            if (n < N) *(f16x8*)&hp_out[(size_t)n * HID + 8 * c8] = *(const f16x8*)&w_lds[row * 136 + 8 * c8];
        }
    } else {
        float b2v = b2[0];
        float treg[4] = {0.f, 0.f, 0.f, 0.f};
#pragma unroll
        for (int c = 0; c < 8; ++c) {
            float b1v = bias[c * 16 + l15];
            float w2v = w2[c * 16 + l15];
#pragma unroll
            for (int r = 0; r < 4; ++r)
                treg[r] += fast_tanh(acc[c][r] + b1v) * w2v;
        }
#pragma unroll
        for (int r = 0; r < 4; ++r) {
            float v = treg[r];
#pragma unroll
            for (int m = 8; m >= 1; m >>= 1) v += __shfl_xor(v, m, 64);
            if (l15 == 0) {
                int n = n0 + wv * 16 + quad * 4 + r;
                if (n < N) escore[n] = __expf(v + b2v);
            }
        }
    }
}

// ================= fused aggregate: lane = (edge-sub 0..3, chan-grp 0..15) =================
// each lane gathers f16x8 (16 B) for its edge; 8 edges in flight per wave iteration.
__global__ void gat_aggregate_kernel(const int* __restrict__ rowptr, const int* __restrict__ esrc,
                                     const float* __restrict__ als, const float* __restrict__ ald,
                                     const _Float16* __restrict__ hp16, const float* __restrict__ gb,
                                     const float* __restrict__ lg, const float* __restrict__ lb,
                                     _Float16* __restrict__ h16, int N) {
    int wave = threadIdx.x >> 6;
    int lane = threadIdx.x & 63;
    int n = blockIdx.x * 4 + wave;
    if (n >= N) return;
    int esub = lane >> 4;          // 0..3: which edge of the group
    int cg = lane & 15;            // channel group: channels cg*8 .. cg*8+7 (single head cg>>1)
    int hd = cg >> 1;
    float adv = ald[n * HEADS + hd];
    int row = rowptr[n], end = rowptr[n + 1];   // end > row (self-loop)
    int last = end - 1;
    float acc[8] = {0.f, 0.f, 0.f, 0.f, 0.f, 0.f, 0.f, 0.f};
    float sw = 0.f;
    for (int base = row; base < end; base += 8) {
        int iA = base + esub, iB = base + 4 + esub;
        int cA = iA <= last ? iA : last;
        int cB = iB <= last ? iB : last;
        int sA = esrc[cA], sB = esrc[cB];
        f16x8 pA = *(const f16x8*)&hp16[(size_t)sA * HID + cg * 8];
        f16x8 pB = *(const f16x8*)&hp16[(size_t)sB * HID + cg * 8];
        float aA = als[sA * HEADS + hd];
        float aB = als[sB * HEADS + hd];
        float mA = (iA < end) ? 1.f : 0.f;
        float mB = (iB < end) ? 1.f : 0.f;
        float lA = aA + adv; lA = lA > 0.f ? lA : 0.2f * lA;
        float lB = aB + adv; lB = lB > 0.f ? lB : 0.2f * lB;
        float wA = __expf(lA) * mA;
        float wB = __expf(lB) * mB;
        sw += wA + wB;
#pragma unroll
        for (int j = 0; j < 8; ++j)
            acc[j] += wA * (float)pA[j] + wB * (float)pB[j];
    }
    // combine the 4 edge-subgroups (lane bits 4,5)
#pragma unroll
    for (int m = 16; m <= 32; m <<= 1) {
        sw += __shfl_xor(sw, m, 64);
#pragma unroll
        for (int j = 0; j < 8; ++j) acc[j] += __shfl_xor(acc[j], m, 64);
    }
    float inv_sw = 1.f / sw;
    float4 g0 = ((const float4*)(gb + cg * 8))[0];
    float4 g1 = ((const float4*)(gb + cg * 8))[1];
    float v[8];
    v[0] = acc[0] * inv_sw + g0.x; v[1] = acc[1] * inv_sw + g0.y;
    v[2] = acc[2] * inv_sw + g0.z; v[3] = acc[3] * inv_sw + g0.w;
    v[4] = acc[4] * inv_sw + g1.x; v[5] = acc[5] * inv_sw + g1.y;
    v[6] = acc[6] * inv_sw + g1.z; v[7] = acc[7] * inv_sw + g1.w;
    // layernorm: each channel appears 4x across the wave -> divide by 512
    float s = 0.f;
#pragma unroll
    for (int j = 0; j < 8; ++j) s += v[j];
#pragma unroll
    for (int m = 32; m >= 1; m >>= 1) s += __shfl_xor(s, m, 64);
    float mu = s * (1.f / 512.f);
    float d[8], sq = 0.f;
#pragma unroll
    for (int j = 0; j < 8; ++j) { d[j] = v[j] - mu; sq += d[j] * d[j]; }
#pragma unroll
    for (int m = 32; m >= 1; m >>= 1) sq += __shfl_xor(sq, m, 64);
    float inv = rsqrtf(sq * (1.f / 512.f) + 1e-5f);
    float4 lg0 = ((const float4*)(lg + cg * 8))[0];
    float4 lg1 = ((const float4*)(lg + cg * 8))[1];
    float4 lb0 = ((const float4*)(lb + cg * 8))[0];
    float4 lb1 = ((const float4*)(lb + cg * 8))[1];
    float lgv[8] = {lg0.x, lg0.y, lg0.z, lg0.w, lg1.x, lg1.y, lg1.z, lg1.w};
    float lbv[8] = {lb0.x, lb0.y, lb0.z, lb0.w, lb1.x, lb1.y, lb1.z, lb1.w};
    f16x8 hold = *(const f16x8*)&h16[(size_t)n * HID + cg * 8];
    f16x8 hnew;
#pragma unroll
    for (int j = 0; j < 8; ++j) {
        float r = d[j] * inv * lgv[j] + lbv[j] + (float)hold[j];
        hnew[j] = (_Float16)(r > 0.f ? r : 0.f);
    }
    if (esub == 0) *(f16x8*)&h16[(size_t)n * HID + cg * 8] = hnew;
}

// ================= per-graph pooling (h16) =================
__global__ void pool_graph_kernel(const _Float16* __restrict__ h16, const float* __restrict__ escore,
                                  const int* __restrict__ gstart, float* __restrict__ sums,
                                  float* __restrict__ cnts, float* __restrict__ hgZ, int G) {
    int g = blockIdx.x;
    int t = threadIdx.x;               // 0..511
    int c = t & 127, grp = t >> 7;     // 4 groups
    int s = gstart[g], e = gstart[g + 1];
    float msum = 0.f, asum = 0.f, z = 0.f;
    for (int n = s + grp; n < e; n += 4) {
        float hv = (float)h16[(size_t)n * HID + c];
        float es = escore[n];
        msum += hv;
        asum += es * hv;
        if (c == 0) z += es;
    }
    __shared__ float sm[4][HID];
    __shared__ float sa[4][HID];
    __shared__ float sz[4];
    sm[grp][c] = msum;
    sa[grp][c] = asum;
    if (c == 0) sz[grp] = z;
    __syncthreads();
    if (t < HID) {
        float m = sm[0][t] + sm[1][t] + sm[2][t] + sm[3][t];
        float a = sa[0][t] + sa[1][t] + sa[2][t] + sa[3][t];
        sums[(size_t)g * HID + t] = m;
        atomicAdd(&hgZ[t], a);
    } else if (t == HID) {
        cnts[g] = (float)(e - s);
        atomicAdd(&hgZ[HID], sz[0] + sz[1] + sz[2] + sz[3]);
    }
}

// ================= classifier head =================
__global__ void head_kernel(const float* __restrict__ hgZ, const float* __restrict__ sums,
                            const float* __restrict__ cnts, const float* __restrict__ W1,
                            const float* __restrict__ b1, const float* __restrict__ W2,
                            const float* __restrict__ b2, float* __restrict__ out, int G) {
    int g = blockIdx.x;
    int t = threadIdx.x;
    __shared__ float hr[HID];
    __shared__ float part[2];
    float Z = hgZ[HID];
    float cnt = cnts[g];
    cnt = cnt > 1.f ? cnt : 1.f;
    hr[t] = hgZ[t] / Z + sums[(size_t)g * HID + t] / cnt;
    __syncthreads();
    float acc = b1[t];
#pragma unroll 8
    for (int k = 0; k < HID; ++k) acc += hr[k] * W1[k * HID + t];
    acc = acc > 0.f ? acc : 0.f;
    float v = acc * W2[t];
#pragma unroll
    for (int m = 32; m >= 1; m >>= 1) v += __shfl_xor(v, m, 64);
    if ((t & 63) == 0) part[t >> 6] = v;
    __syncthreads();
    if (t == 0) out[g] = part[0] + part[1] + b2[0];
}

extern "C" void kernel_launch(void* const* d_in, const int* in_sizes, int n_in,
                              void* d_out, int out_size, void* d_ws, size_t ws_size,
                              hipStream_t stream) {
    const float* x        = (const float*)d_in[0];
    const int*   ei       = (const int*)d_in[1];
    const int*   ntypes   = (const int*)d_in[2];
    const int*   batch    = (const int*)d_in[3];
    const float* emb_W    = (const float*)d_in[4];
    const float* emb_b    = (const float*)d_in[5];
    const float* nemb     = (const float*)d_in[6];
    const float* gat_W    = (const float*)d_in[7];
    const float* att_src  = (const float*)d_in[8];
    const float* att_dst  = (const float*)d_in[9];
    const float* gat_b    = (const float*)d_in[10];
    const float* ln_g     = (const float*)d_in[11];
    const float* ln_b     = (const float*)d_in[12];
    const float* ga_W1    = (const float*)d_in[13];
    const float* ga_b1    = (const float*)d_in[14];
    const float* ga_W2    = (const float*)d_in[15];
    const float* ga_b2    = (const float*)d_in[16];
    const float* cls_W1   = (const float*)d_in[17];
    const float* cls_b1   = (const float*)d_in[18];
    const float* cls_W2   = (const float*)d_in[19];
    const float* cls_b2   = (const float*)d_in[20];
    float* out = (float*)d_out;

    const int N  = in_sizes[2];
    const int E  = in_sizes[1] / 2;
    const int EE = E + N;
    const int G  = out_size;
    const int NB = (N + 255) / 256;

    float* ws      = (float*)d_ws;
    float* als     = ws;                               // N*8
    float* ald     = als + (size_t)N * HEADS;          // N*8
    float* escore  = ald + (size_t)N * HEADS;          // N
    float* sums    = escore + N;                       // G*128
    float* cnts    = sums + (size_t)G * HID;           // G
    float* hgZ     = cnts + G;                         // 129
    _Float16* h16  = (_Float16*)(hgZ + HID + 1);       // N*128
    _Float16* hp16 = h16 + (size_t)N * HID;            // N*128
    _Float16* x16  = hp16 + (size_t)N * HID;           // N*64
    _Float16* wt_emb = x16 + (size_t)N * INDIM;        // 128*64
    _Float16* wt_gat = wt_emb + 128 * 64;              // 3*128*128
    _Float16* wt_ga1 = wt_gat + 3 * 128 * 128;         // 128*128
    int*   rowptr  = (int*)(wt_ga1 + 128 * 128);       // N+1
    int*   woff    = rowptr + (N + 1);                 // N
    int*   deg     = woff + N;                         // N
    int*   esrc    = deg + N;                          // EE
    int*   partials= esrc + EE;                        // NB
    int*   gstart  = partials + NB;                    // G+1

    // ---- CSR build + converts ----
    hipMemsetAsync(deg, 0, (size_t)N * sizeof(int), stream);
    hipMemsetAsync(hgZ, 0, (HID + 1) * sizeof(float), stream);
    count_kernel<<<(EE + 255) / 256, 256, 0, stream>>>(ei, deg, E, EE);
    block_sum_kernel<<<NB, 256, 0, stream>>>(deg, partials, N);
    scan_partials_kernel<<<1, 64, 0, stream>>>(partials, NB);
    rowptr_kernel<<<NB, 256, 0, stream>>>(deg, partials, rowptr, woff, N, EE);
    scatter_kernel<<<(EE + 255) / 256, 256, 0, stream>>>(ei, woff, esrc, E, EE);
    gstart_kernel<<<(G + 64) / 64, 64, 0, stream>>>(batch, gstart, N, G);
    convert_x_kernel<<<(N * INDIM / 4 + 255) / 256, 256, 0, stream>>>(x, x16, N * INDIM / 4);
    convert_w_kernel<<<(73728 + 255) / 256, 256, 0, stream>>>(
        emb_W, gat_W, ga_W1, wt_emb, wt_gat, wt_ga1);

    const int PB = (N + 63) / 64;

    // ---- network ----
    mfma_proj_kernel<<<PB, 256, 0, stream>>>(
        0, INDIM, N, x16, wt_emb, emb_b, nemb, ntypes, h16,
        nullptr, nullptr, nullptr, nullptr, nullptr, nullptr, nullptr, nullptr);

    for (int l = 0; l < 3; ++l) {
        mfma_proj_kernel<<<PB, 256, 0, stream>>>(
            1, HID, N, h16, wt_gat + (size_t)l * HID * HID,
            nullptr, nullptr, nullptr, nullptr,
            att_src + l * HID, att_dst + l * HID,
            hp16, als, ald, nullptr, nullptr, nullptr);
        gat_aggregate_kernel<<<(N + 3) / 4, 256, 0, stream>>>(
            rowptr, esrc, als, ald, hp16,
            gat_b + l * HID, ln_g + l * HID, ln_b + l * HID, h16, N);
    }

    mfma_proj_kernel<<<PB, 256, 0, stream>>>(
        2, HID, N, h16, wt_ga1, ga_b1, nullptr, nullptr, nullptr,
        nullptr, nullptr, nullptr, nullptr, nullptr, ga_W2, ga_b2, escore);

    pool_graph_kernel<<<G, 512, 0, stream>>>(h16, escore, gstart, sums, cnts, hgZ, G);
    head_kernel<<<G, 128, 0, stream>>>(hgZ, sums, cnts, cls_W1, cls_b1, cls_W2, cls_b2, out, G);
}

// Round 9
// 427.613 us; speedup vs baseline: 1.7523x; 1.0231x over previous
//
#include <hip/hip_runtime.h>
#include <hip/hip_bf16.h>
#include <math.h>

#define HID 128
#define HEADS 8
#define INDIM 64

typedef _Float16 f16x8 __attribute__((ext_vector_type(8)));
typedef _Float16 f16x4 __attribute__((ext_vector_type(4)));
typedef _Float16 f16x2 __attribute__((ext_vector_type(2)));
typedef float f32x4 __attribute__((ext_vector_type(4)));

__device__ __forceinline__ float fast_tanh(float x) {
    return 1.f - 2.f / (__expf(2.f * x) + 1.f);
}

#if defined(__has_builtin)
#if __has_builtin(__builtin_amdgcn_fdot2)
#define HAVE_FDOT2 1
#endif
#endif

// ================= CSR build (by dst) =================

__global__ void count_kernel(const int* __restrict__ ei, int* __restrict__ deg, int E, int EE) {
    int e = blockIdx.x * blockDim.x + threadIdx.x;
    if (e >= EE) return;
    int dst = (e < E) ? ei[E + e] : (e - E);
    atomicAdd(&deg[dst], 1);
}

__global__ void block_sum_kernel(const int* __restrict__ deg, int* __restrict__ partials, int N) {
    __shared__ int sdata[4];
    int t = threadIdx.x;
    int i = blockIdx.x * 256 + t;
    int v = (i < N) ? deg[i] : 0;
#pragma unroll
    for (int m = 32; m >= 1; m >>= 1) v += __shfl_xor(v, m, 64);
    if ((t & 63) == 0) sdata[t >> 6] = v;
    __syncthreads();
    if (t == 0) partials[blockIdx.x] = sdata[0] + sdata[1] + sdata[2] + sdata[3];
}

__global__ void scan_partials_kernel(int* __restrict__ partials, int nb) {
    int lane = threadIdx.x;  // 64 threads
    int carry = 0;
    for (int base = 0; base < nb; base += 64) {
        int i = base + lane;
        int v = (i < nb) ? partials[i] : 0;
        int orig = v;
#pragma unroll
        for (int off = 1; off < 64; off <<= 1) {
            int x = __shfl_up(v, off, 64);
            if (lane >= off) v += x;
        }
        if (i < nb) partials[i] = v - orig + carry;
        carry += __shfl(v, 63, 64);
    }
}

__global__ void rowptr_kernel(const int* __restrict__ deg, const int* __restrict__ partials,
                              int* __restrict__ rowptr, int* __restrict__ woff, int N, int EE) {
    __shared__ int tmp[256];
    int t = threadIdx.x;
    int i = blockIdx.x * 256 + t;
    int v = (i < N) ? deg[i] : 0;
    tmp[t] = v;
    __syncthreads();
#pragma unroll
    for (int off = 1; off < 256; off <<= 1) {
        int x = (t >= off) ? tmp[t - off] : 0;
        __syncthreads();
        tmp[t] += x;
        __syncthreads();
    }
    int excl = tmp[t] - v + partials[blockIdx.x];
    if (i < N) { rowptr[i] = excl; woff[i] = excl; }
    if (blockIdx.x == 0 && t == 0) rowptr[N] = EE;
}

__global__ void scatter_kernel(const int* __restrict__ ei, int* __restrict__ woff,
                               int* __restrict__ esrc, int E, int EE) {
    int e = blockIdx.x * blockDim.x + threadIdx.x;
    if (e >= EE) return;
    int src, dst;
    if (e < E) { src = ei[e]; dst = ei[E + e]; } else { src = dst = e - E; }
    int slot = atomicAdd(&woff[dst], 1);
    esrc[slot] = src;
}

__global__ void gstart_kernel(const int* __restrict__ batch, int* __restrict__ gstart,
                              int N, int G) {
    int g = blockIdx.x * blockDim.x + threadIdx.x;
    if (g > G) return;
    int lo = 0, hi = N;
    while (lo < hi) {
        int mid = (lo + hi) >> 1;
        if (batch[mid] < g) lo = mid + 1; else hi = mid;
    }
    gstart[g] = lo;
}

// ================= converts =================
__global__ void convert_x_kernel(const float* __restrict__ x, _Float16* __restrict__ x16, int tot4) {
    int i = blockIdx.x * blockDim.x + threadIdx.x;
    if (i >= tot4) return;
    float4 v = ((const float4*)x)[i];
    f16x4 o; o[0] = (_Float16)v.x; o[1] = (_Float16)v.y; o[2] = (_Float16)v.z; o[3] = (_Float16)v.w;
    *(f16x4*)&x16[4 * i] = o;
}

__global__ void convert_w_kernel(const float* __restrict__ emb_W, const float* __restrict__ gat_W,
                                 const float* __restrict__ ga_W1, _Float16* __restrict__ wt_emb,
                                 _Float16* __restrict__ wt_gat, _Float16* __restrict__ wt_ga1) {
    int i = blockIdx.x * blockDim.x + threadIdx.x;
    if (i < 8192) {                       // emb_W [64][128]
        int k = i >> 7, n = i & 127;
        wt_emb[n * 64 + k] = (_Float16)emb_W[i];
    } else if (i < 8192 + 49152) {        // gat_W [3][128][128]
        int j = i - 8192;
        int l = j >> 14, r = j & 16383;
        int k = r >> 7, n = r & 127;
        wt_gat[l * 16384 + n * 128 + k] = (_Float16)gat_W[j];
    } else if (i < 73728) {               // ga_W1 [128][128]
        int j = i - 57344;
        int k = j >> 7, n = j & 127;
        wt_ga1[n * 128 + k] = (_Float16)ga_W1[j];
    }
}

// ================= unified MFMA projection kernel =================
// C[64 x 128] = A16[64 x K] @ W[K x 128]; A staged via LDS (coalesced).
// mode 0: embed epilogue (bias + ntype_emb -> h16)
// mode 1: GAT proj epilogue (hp16 store + als/ald via LDS transpose)
// mode 2: score epilogue (tanh MLP -> escore)
__global__ __launch_bounds__(256) void mfma_proj_kernel(
    int mode, int K, int N,
    const _Float16* __restrict__ A16, const _Float16* __restrict__ Wt,
    const float* __restrict__ bias, const float* __restrict__ nemb,
    const int* __restrict__ ntypes, _Float16* __restrict__ h16out,
    const float* __restrict__ asrc, const float* __restrict__ adst,
    _Float16* __restrict__ hp_out, float* __restrict__ als, float* __restrict__ ald,
    const float* __restrict__ w2, const float* __restrict__ b2,
    float* __restrict__ escore)
{
    __shared__ _Float16 w_lds[128 * 136];   // 34.8 KB
    __shared__ _Float16 a_lds[64 * 136];    // 17.4 KB
    int t = threadIdx.x;
    int n0 = blockIdx.x * 64;
    int KP = K + 8;

    int K8 = K >> 3;
    // stage W (coalesced)
    for (int i = t; i < 128 * K8; i += 256) {
        int row = i / K8, c8 = i - row * K8;
        *(f16x8*)&w_lds[row * KP + 8 * c8] = *(const f16x8*)&Wt[(size_t)row * K + 8 * c8];
    }
    // stage A (coalesced)
    for (int i = t; i < 64 * K8; i += 256) {
        int row = i / K8, c8 = i - row * K8;
        f16x8 v = {};
        if (n0 + row < N) v = *(const f16x8*)&A16[(size_t)(n0 + row) * K + 8 * c8];
        *(f16x8*)&a_lds[row * KP + 8 * c8] = v;
    }
    __syncthreads();

    int lane = t & 63, wv = t >> 6;
    int l15 = lane & 15, quad = lane >> 4;

    f32x4 acc[8];
#pragma unroll
    for (int c = 0; c < 8; ++c) acc[c] = (f32x4){0.f, 0.f, 0.f, 0.f};

    int ksteps = K >> 5;
    for (int kk = 0; kk < ksteps; ++kk) {
        f16x8 af = *(const f16x8*)&a_lds[(wv * 16 + l15) * KP + kk * 32 + quad * 8];
#pragma unroll
        for (int c = 0; c < 8; ++c) {
            f16x8 bf = *(const f16x8*)&w_lds[(c * 16 + l15) * KP + kk * 32 + quad * 8];
            acc[c] = __builtin_amdgcn_mfma_f32_16x16x32_f16(af, bf, acc[c], 0, 0, 0);
        }
    }

    // C layout: row = wv*16 + quad*4 + r, col = c*16 + l15
    if (mode == 0) {
        float bv[8];
#pragma unroll
        for (int c = 0; c < 8; ++c) bv[c] = bias[c * 16 + l15];
        __syncthreads();
#pragma unroll
        for (int r = 0; r < 4; ++r) {
            int n = n0 + wv * 16 + quad * 4 + r;
            int nt = (n < N) ? ntypes[n] : 0;
#pragma unroll
            for (int c = 0; c < 8; ++c)
                a_lds[(wv * 16 + quad * 4 + r) * 136 + c * 16 + l15] =
                    (_Float16)(acc[c][r] + bv[c] + nemb[nt * HID + c * 16 + l15]);
        }
        __syncthreads();
        for (int i = t; i < 64 * 16; i += 256) {
            int row = i >> 4, c8 = i & 15;
            int n = n0 + row;
            if (n < N) *(f16x8*)&h16out[(size_t)n * HID + 8 * c8] = *(const f16x8*)&a_lds[row * 136 + 8 * c8];
        }
    } else if (mode == 1) {
        __syncthreads();
#pragma unroll
        for (int c = 0; c < 8; ++c)
#pragma unroll
            for (int r = 0; r < 4; ++r)
                a_lds[(wv * 16 + quad * 4 + r) * 136 + c * 16 + l15] = (_Float16)acc[c][r];
        __syncthreads();
        // hp16 store (coalesced 16B)
        for (int i = t; i < 64 * 16; i += 256) {
            int row = i >> 4, c8 = i & 15;
            int n = n0 + row;
            if (n < N) *(f16x8*)&hp_out[(size_t)n * HID + 8 * c8] = *(const f16x8*)&a_lds[row * 136 + 8 * c8];
        }
        // als/ald from LDS transpose: task = row*8 + head
        for (int task = t; task < 512; task += 256) {
            int row = task >> 3, hd = task & 7;
            int n = n0 + row;
            if (n >= N) continue;
            f16x8 v0 = *(const f16x8*)&a_lds[row * 136 + hd * 16];
            f16x8 v1 = *(const f16x8*)&a_lds[row * 136 + hd * 16 + 8];
            float va = 0.f, vd = 0.f;
#pragma unroll
            for (int j = 0; j < 8; ++j) {
                va += (float)v0[j] * asrc[hd * 16 + j] + (float)v1[j] * asrc[hd * 16 + 8 + j];
                vd += (float)v0[j] * adst[hd * 16 + j] + (float)v1[j] * adst[hd * 16 + 8 + j];
            }
            als[n * HEADS + hd] = va;
            ald[n * HEADS + hd] = vd;
        }
    } else {
        float b2v = b2[0];
        float treg[4] = {0.f, 0.f, 0.f, 0.f};
#pragma unroll
        for (int c = 0; c < 8; ++c) {
            float b1v = bias[c * 16 + l15];
            float w2v = w2[c * 16 + l15];
#pragma unroll
            for (int r = 0; r < 4; ++r)
                treg[r] += fast_tanh(acc[c][r] + b1v) * w2v;
        }
#pragma unroll
        for (int r = 0; r < 4; ++r) {
            float v = treg[r];
#pragma unroll
            for (int m = 8; m >= 1; m >>= 1) v += __shfl_xor(v, m, 64);
            if (l15 == 0) {
                int n = n0 + wv * 16 + quad * 4 + r;
                if (n < N) escore[n] = __expf(v + b2v);
            }
        }
    }
}

// ================= fused aggregate: 16 edges in flight, packed fdot2 =================
// lane = (edge-sub 0..3, chan-grp 0..15); each lane gathers 4x f16x8 per iteration.
__global__ void gat_aggregate_kernel(const int* __restrict__ rowptr, const int* __restrict__ esrc,
                                     const float* __restrict__ als, const float* __restrict__ ald,
                                     const _Float16* __restrict__ hp16, const float* __restrict__ gb,
                                     const float* __restrict__ lg, const float* __restrict__ lb,
                                     _Float16* __restrict__ h16, int N) {
    int wave = threadIdx.x >> 6;
    int lane = threadIdx.x & 63;
    int n = blockIdx.x * 4 + wave;
    if (n >= N) return;
    int esub = lane >> 4;          // 0..3
    int cg = lane & 15;            // channels cg*8 .. cg*8+7 (head cg>>1)
    int hd = cg >> 1;
    float adv = ald[n * HEADS + hd];
    int row = rowptr[n], end = rowptr[n + 1];   // end > row (self-loop)
    int last = end - 1;
    float acc[8] = {0.f, 0.f, 0.f, 0.f, 0.f, 0.f, 0.f, 0.f};
    float sw = 0.f;
    for (int base = row; base < end; base += 16) {
        int iA = base + esub;
        int iB = iA + 4, iC = iA + 8, iD = iA + 12;
        int cA = iA <= last ? iA : last;
        int cB = iB <= last ? iB : last;
        int cC = iC <= last ? iC : last;
        int cD = iD <= last ? iD : last;
        int sA = esrc[cA], sB = esrc[cB], sC = esrc[cC], sD = esrc[cD];
        f16x8 pA = *(const f16x8*)&hp16[(size_t)sA * HID + cg * 8];
        f16x8 pB = *(const f16x8*)&hp16[(size_t)sB * HID + cg * 8];
        f16x8 pC = *(const f16x8*)&hp16[(size_t)sC * HID + cg * 8];
        f16x8 pD = *(const f16x8*)&hp16[(size_t)sD * HID + cg * 8];
        float aA = als[sA * HEADS + hd];
        float aB = als[sB * HEADS + hd];
        float aC = als[sC * HEADS + hd];
        float aD = als[sD * HEADS + hd];
        float lA = aA + adv; lA = lA > 0.f ? lA : 0.2f * lA;
        float lB = aB + adv; lB = lB > 0.f ? lB : 0.2f * lB;
        float lC = aC + adv; lC = lC > 0.f ? lC : 0.2f * lC;
        float lD = aD + adv; lD = lD > 0.f ? lD : 0.2f * lD;
        float wA = __expf(lA) * ((iA < end) ? 1.f : 0.f);
        float wB = __expf(lB) * ((iB < end) ? 1.f : 0.f);
        float wC = __expf(lC) * ((iC < end) ? 1.f : 0.f);
        float wD = __expf(lD) * ((iD < end) ? 1.f : 0.f);
        sw += (wA + wB) + (wC + wD);
#ifdef HAVE_FDOT2
        f16x2 wAB; wAB[0] = (_Float16)wA; wAB[1] = (_Float16)wB;
        f16x2 wCD; wCD[0] = (_Float16)wC; wCD[1] = (_Float16)wD;
#pragma unroll
        for (int j = 0; j < 8; ++j) {
            f16x2 prAB; prAB[0] = pA[j]; prAB[1] = pB[j];
            f16x2 prCD; prCD[0] = pC[j]; prCD[1] = pD[j];
            acc[j] = __builtin_amdgcn_fdot2(prAB, wAB, acc[j], false);
            acc[j] = __builtin_amdgcn_fdot2(prCD, wCD, acc[j], false);
        }
#else
#pragma unroll
        for (int j = 0; j < 8; ++j)
            acc[j] += wA * (float)pA[j] + wB * (float)pB[j]
                    + wC * (float)pC[j] + wD * (float)pD[j];
#endif
    }
    // combine the 4 edge-subgroups (lane bits 4,5)
#pragma unroll
    for (int m = 16; m <= 32; m <<= 1) {
        sw += __shfl_xor(sw, m, 64);
#pragma unroll
        for (int j = 0; j < 8; ++j) acc[j] += __shfl_xor(acc[j], m, 64);
    }
    float inv_sw = 1.f / sw;
    float4 g0 = ((const float4*)(gb + cg * 8))[0];
    float4 g1 = ((const float4*)(gb + cg * 8))[1];
    float v[8];
    v[0] = acc[0] * inv_sw + g0.x; v[1] = acc[1] * inv_sw + g0.y;
    v[2] = acc[2] * inv_sw + g0.z; v[3] = acc[3] * inv_sw + g0.w;
    v[4] = acc[4] * inv_sw + g1.x; v[5] = acc[5] * inv_sw + g1.y;
    v[6] = acc[6] * inv_sw + g1.z; v[7] = acc[7] * inv_sw + g1.w;
    // layernorm: each channel appears 4x across the wave -> /512
    float s = 0.f;
#pragma unroll
    for (int j = 0; j < 8; ++j) s += v[j];
#pragma unroll
    for (int m = 32; m >= 1; m >>= 1) s += __shfl_xor(s, m, 64);
    float mu = s * (1.f / 512.f);
    float d[8], sq = 0.f;
#pragma unroll
    for (int j = 0; j < 8; ++j) { d[j] = v[j] - mu; sq += d[j] * d[j]; }
#pragma unroll
    for (int m = 32; m >= 1; m >>= 1) sq += __shfl_xor(sq, m, 64);
    float inv = rsqrtf(sq * (1.f / 512.f) + 1e-5f);
    float4 lg0 = ((const float4*)(lg + cg * 8))[0];
    float4 lg1 = ((const float4*)(lg + cg * 8))[1];
    float4 lb0 = ((const float4*)(lb + cg * 8))[0];
    float4 lb1 = ((const float4*)(lb + cg * 8))[1];
    float lgv[8] = {lg0.x, lg0.y, lg0.z, lg0.w, lg1.x, lg1.y, lg1.z, lg1.w};
    float lbv[8] = {lb0.x, lb0.y, lb0.z, lb0.w, lb1.x, lb1.y, lb1.z, lb1.w};
    f16x8 hold = *(const f16x8*)&h16[(size_t)n * HID + cg * 8];
    f16x8 hnew;
#pragma unroll
    for (int j = 0; j < 8; ++j) {
        float r = d[j] * inv * lgv[j] + lbv[j] + (float)hold[j];
        hnew[j] = (_Float16)(r > 0.f ? r : 0.f);
    }
    if (esub == 0) *(f16x8*)&h16[(size_t)n * HID + cg * 8] = hnew;
}

// ================= per-graph pooling (h16) =================
__global__ void pool_graph_kernel(const _Float16* __restrict__ h16, const float* __restrict__ escore,
                                  const int* __restrict__ gstart, float* __restrict__ sums,
                                  float* __restrict__ cnts, float* __restrict__ hgZ, int G) {
    int g = blockIdx.x;
    int t = threadIdx.x;               // 0..511
    int c = t & 127, grp = t >> 7;     // 4 groups
    int s = gstart[g], e = gstart[g + 1];
    float msum = 0.f, asum = 0.f, z = 0.f;
    for (int n = s + grp; n < e; n += 4) {
        float hv = (float)h16[(size_t)n * HID + c];
        float es = escore[n];
        msum += hv;
        asum += es * hv;
        if (c == 0) z += es;
    }
    __shared__ float sm[4][HID];
    __shared__ float sa[4][HID];
    __shared__ float sz[4];
    sm[grp][c] = msum;
    sa[grp][c] = asum;
    if (c == 0) sz[grp] = z;
    __syncthreads();
    if (t < HID) {
        float m = sm[0][t] + sm[1][t] + sm[2][t] + sm[3][t];
        float a = sa[0][t] + sa[1][t] + sa[2][t] + sa[3][t];
        sums[(size_t)g * HID + t] = m;
        atomicAdd(&hgZ[t], a);
    } else if (t == HID) {
        cnts[g] = (float)(e - s);
        atomicAdd(&hgZ[HID], sz[0] + sz[1] + sz[2] + sz[3]);
    }
}

// ================= classifier head =================
__global__ void head_kernel(const float* __restrict__ hgZ, const float* __restrict__ sums,
                            const float* __restrict__ cnts, const float* __restrict__ W1,
                            const float* __restrict__ b1, const float* __restrict__ W2,
                            const float* __restrict__ b2, float* __restrict__ out, int G) {
    int g = blockIdx.x;
    int t = threadIdx.x;
    __shared__ float hr[HID];
    __shared__ float part[2];
    float Z = hgZ[HID];
    float cnt = cnts[g];
    cnt = cnt > 1.f ? cnt : 1.f;
    hr[t] = hgZ[t] / Z + sums[(size_t)g * HID + t] / cnt;
    __syncthreads();
    float acc = b1[t];
#pragma unroll 8
    for (int k = 0; k < HID; ++k) acc += hr[k] * W1[k * HID + t];
    acc = acc > 0.f ? acc : 0.f;
    float v = acc * W2[t];
#pragma unroll
    for (int m = 32; m >= 1; m >>= 1) v += __shfl_xor(v, m, 64);
    if ((t & 63) == 0) part[t >> 6] = v;
    __syncthreads();
    if (t == 0) out[g] = part[0] + part[1] + b2[0];
}

extern "C" void kernel_launch(void* const* d_in, const int* in_sizes, int n_in,
                              void* d_out, int out_size, void* d_ws, size_t ws_size,
                              hipStream_t stream) {
    const float* x        = (const float*)d_in[0];
    const int*   ei       = (const int*)d_in[1];
    const int*   ntypes   = (const int*)d_in[2];
    const int*   batch    = (const int*)d_in[3];
    const float* emb_W    = (const float*)d_in[4];
    const float* emb_b    = (const float*)d_in[5];
    const float* nemb     = (const float*)d_in[6];
    const float* gat_W    = (const float*)d_in[7];
    const float* att_src  = (const float*)d_in[8];
    const float* att_dst  = (const float*)d_in[9];
    const float* gat_b    = (const float*)d_in[10];
    const float* ln_g     = (const float*)d_in[11];
    const float* ln_b     = (const float*)d_in[12];
    const float* ga_W1    = (const float*)d_in[13];
    const float* ga_b1    = (const float*)d_in[14];
    const float* ga_W2    = (const float*)d_in[15];
    const float* ga_b2    = (const float*)d_in[16];
    const float* cls_W1   = (const float*)d_in[17];
    const float* cls_b1   = (const float*)d_in[18];
    const float* cls_W2   = (const float*)d_in[19];
    const float* cls_b2   = (const float*)d_in[20];
    float* out = (float*)d_out;

    const int N  = in_sizes[2];
    const int E  = in_sizes[1] / 2;
    const int EE = E + N;
    const int G  = out_size;
    const int NB = (N + 255) / 256;

    float* ws      = (float*)d_ws;
    float* als     = ws;                               // N*8
    float* ald     = als + (size_t)N * HEADS;          // N*8
    float* escore  = ald + (size_t)N * HEADS;          // N
    float* sums    = escore + N;                       // G*128
    float* cnts    = sums + (size_t)G * HID;           // G
    float* hgZ     = cnts + G;                         // 129
    _Float16* h16  = (_Float16*)(hgZ + HID + 1);       // N*128
    _Float16* hp16 = h16 + (size_t)N * HID;            // N*128
    _Float16* x16  = hp16 + (size_t)N * HID;           // N*64
    _Float16* wt_emb = x16 + (size_t)N * INDIM;        // 128*64
    _Float16* wt_gat = wt_emb + 128 * 64;              // 3*128*128
    _Float16* wt_ga1 = wt_gat + 3 * 128 * 128;         // 128*128
    int*   rowptr  = (int*)(wt_ga1 + 128 * 128);       // N+1
    int*   woff    = rowptr + (N + 1);                 // N
    int*   deg     = woff + N;                         // N
    int*   esrc    = deg + N;                          // EE
    int*   partials= esrc + EE;                        // NB
    int*   gstart  = partials + NB;                    // G+1

    // ---- CSR build + converts ----
    hipMemsetAsync(deg, 0, (size_t)N * sizeof(int), stream);
    hipMemsetAsync(hgZ, 0, (HID + 1) * sizeof(float), stream);
    count_kernel<<<(EE + 255) / 256, 256, 0, stream>>>(ei, deg, E, EE);
    block_sum_kernel<<<NB, 256, 0, stream>>>(deg, partials, N);
    scan_partials_kernel<<<1, 64, 0, stream>>>(partials, NB);
    rowptr_kernel<<<NB, 256, 0, stream>>>(deg, partials, rowptr, woff, N, EE);
    scatter_kernel<<<(EE + 255) / 256, 256, 0, stream>>>(ei, woff, esrc, E, EE);
    gstart_kernel<<<(G + 64) / 64, 64, 0, stream>>>(batch, gstart, N, G);
    convert_x_kernel<<<(N * INDIM / 4 + 255) / 256, 256, 0, stream>>>(x, x16, N * INDIM / 4);
    convert_w_kernel<<<(73728 + 255) / 256, 256, 0, stream>>>(
        emb_W, gat_W, ga_W1, wt_emb, wt_gat, wt_ga1);

    const int PB = (N + 63) / 64;

    // ---- network ----
    mfma_proj_kernel<<<PB, 256, 0, stream>>>(
        0, INDIM, N, x16, wt_emb, emb_b, nemb, ntypes, h16,
        nullptr, nullptr, nullptr, nullptr, nullptr, nullptr, nullptr, nullptr);

    for (int l = 0; l < 3; ++l) {
        mfma_proj_kernel<<<PB, 256, 0, stream>>>(
            1, HID, N, h16, wt_gat + (size_t)l * HID * HID,
            nullptr, nullptr, nullptr, nullptr,
            att_src + l * HID, att_dst + l * HID,
            hp16, als, ald, nullptr, nullptr, nullptr);
        gat_aggregate_kernel<<<(N + 3) / 4, 256, 0, stream>>>(
            rowptr, esrc, als, ald, hp16,
            gat_b + l * HID, ln_g + l * HID, ln_b + l * HID, h16, N);
    }

    mfma_proj_kernel<<<PB, 256, 0, stream>>>(
        2, HID, N, h16, wt_ga1, ga_b1, nullptr, nullptr, nullptr,
        nullptr, nullptr, nullptr, nullptr, nullptr, ga_W2, ga_b2, escore);

    pool_graph_kernel<<<G, 512, 0, stream>>>(h16, escore, gstart, sums, cnts, hgZ, G);
    head_kernel<<<G, 128, 0, stream>>>(hgZ, sums, cnts, cls_W1, cls_b1, cls_W2, cls_b2, out, G);
}

// Round 10
// 402.300 us; speedup vs baseline: 1.8626x; 1.0629x over previous
//
#include <hip/hip_runtime.h>
#include <hip/hip_bf16.h>
#include <math.h>

#define HID 128
#define HEADS 8
#define INDIM 64

typedef _Float16 f16x8 __attribute__((ext_vector_type(8)));
typedef _Float16 f16x4 __attribute__((ext_vector_type(4)));
typedef _Float16 f16x2 __attribute__((ext_vector_type(2)));
typedef float f32x4 __attribute__((ext_vector_type(4)));

__device__ __forceinline__ float fast_tanh(float x) {
    return 1.f - 2.f / (__expf(2.f * x) + 1.f);
}

#if defined(__has_builtin)
#if __has_builtin(__builtin_amdgcn_fdot2)
#define HAVE_FDOT2 1
#endif
#endif

// ================= fused prologue: count + convert_x + convert_w + gstart + hgZ zero ==========
__global__ void prologue_kernel(const int* __restrict__ ei, int* __restrict__ deg,
                                const float* __restrict__ x, _Float16* __restrict__ x16,
                                const float* __restrict__ emb_W, const float* __restrict__ gat_W,
                                const float* __restrict__ ga_W1, _Float16* __restrict__ wt_emb,
                                _Float16* __restrict__ wt_gat, _Float16* __restrict__ wt_ga1,
                                const int* __restrict__ batch, int* __restrict__ gstart,
                                float* __restrict__ hgZ,
                                int E, int EE, int N, int G, int XT4) {
    int i = blockIdx.x * blockDim.x + threadIdx.x;
    // x fp32 -> f16 (vector4)
    if (i < XT4) {
        float4 v = ((const float4*)x)[i];
        f16x4 o; o[0] = (_Float16)v.x; o[1] = (_Float16)v.y; o[2] = (_Float16)v.z; o[3] = (_Float16)v.w;
        *(f16x4*)&x16[4 * i] = o;
    }
    // degree histogram
    if (i < EE) {
        int dst = (i < E) ? ei[E + i] : (i - E);
        atomicAdd(&deg[dst], 1);
    }
    // weight transposes fp32 -> f16
    if (i < 8192) {                       // emb_W [64][128]
        int k = i >> 7, n = i & 127;
        wt_emb[n * 64 + k] = (_Float16)emb_W[i];
    } else if (i < 8192 + 49152) {        // gat_W [3][128][128]
        int j = i - 8192;
        int l = j >> 14, r = j & 16383;
        int k = r >> 7, n = r & 127;
        wt_gat[l * 16384 + n * 128 + k] = (_Float16)gat_W[j];
    } else if (i < 73728) {               // ga_W1 [128][128]
        int j = i - 57344;
        int k = j >> 7, n = j & 127;
        wt_ga1[n * 128 + k] = (_Float16)ga_W1[j];
    } else if (i < 73728 + 129) {         // hgZ zero
        hgZ[i - 73728] = 0.f;
    }
    // graph boundaries (batch sorted)
    if (i >= 100000 && i - 100000 <= G) {
        int g = i - 100000;
        int lo = 0, hi = N;
        while (lo < hi) {
            int mid = (lo + hi) >> 1;
            if (batch[mid] < g) lo = mid + 1; else hi = mid;
        }
        gstart[g] = lo;
    }
}

// ================= CSR scan chain =================
__global__ void block_sum_kernel(const int* __restrict__ deg, int* __restrict__ partials, int N) {
    __shared__ int sdata[4];
    int t = threadIdx.x;
    int i = blockIdx.x * 256 + t;
    int v = (i < N) ? deg[i] : 0;
#pragma unroll
    for (int m = 32; m >= 1; m >>= 1) v += __shfl_xor(v, m, 64);
    if ((t & 63) == 0) sdata[t >> 6] = v;
    __syncthreads();
    if (t == 0) partials[blockIdx.x] = sdata[0] + sdata[1] + sdata[2] + sdata[3];
}

__global__ void scan_partials_kernel(int* __restrict__ partials, int nb) {
    int lane = threadIdx.x;  // 64 threads
    int carry = 0;
    for (int base = 0; base < nb; base += 64) {
        int i = base + lane;
        int v = (i < nb) ? partials[i] : 0;
        int orig = v;
#pragma unroll
        for (int off = 1; off < 64; off <<= 1) {
            int x = __shfl_up(v, off, 64);
            if (lane >= off) v += x;
        }
        if (i < nb) partials[i] = v - orig + carry;
        carry += __shfl(v, 63, 64);
    }
}

__global__ void rowptr_kernel(const int* __restrict__ deg, const int* __restrict__ partials,
                              int* __restrict__ rowptr, int* __restrict__ woff, int N, int EE) {
    __shared__ int tmp[256];
    int t = threadIdx.x;
    int i = blockIdx.x * 256 + t;
    int v = (i < N) ? deg[i] : 0;
    tmp[t] = v;
    __syncthreads();
#pragma unroll
    for (int off = 1; off < 256; off <<= 1) {
        int x = (t >= off) ? tmp[t - off] : 0;
        __syncthreads();
        tmp[t] += x;
        __syncthreads();
    }
    int excl = tmp[t] - v + partials[blockIdx.x];
    if (i < N) { rowptr[i] = excl; woff[i] = excl; }
    if (blockIdx.x == 0 && t == 0) rowptr[N] = EE;
}

__global__ void scatter_kernel(const int* __restrict__ ei, int* __restrict__ woff,
                               int* __restrict__ esrc, int E, int EE) {
    int e = blockIdx.x * blockDim.x + threadIdx.x;
    if (e >= EE) return;
    int src, dst;
    if (e < E) { src = ei[e]; dst = ei[E + e]; } else { src = dst = e - E; }
    int slot = atomicAdd(&woff[dst], 1);
    esrc[slot] = src;
}

// ================= unified MFMA projection kernel (2 row-tiles per block) =================
// C[64 x 128] = A16[64 x K] @ W[K x 128]; A staged via LDS (coalesced); W staged once.
// mode 0: embed epilogue (bias + ntype_emb -> h16)
// mode 1: GAT proj epilogue (hp16 store + als/ald via LDS transpose)
// mode 2: score epilogue (tanh MLP -> escore)
__global__ __launch_bounds__(256) void mfma_proj_kernel(
    int mode, int K, int N,
    const _Float16* __restrict__ A16, const _Float16* __restrict__ Wt,
    const float* __restrict__ bias, const float* __restrict__ nemb,
    const int* __restrict__ ntypes, _Float16* __restrict__ h16out,
    const float* __restrict__ asrc, const float* __restrict__ adst,
    _Float16* __restrict__ hp_out, float* __restrict__ als, float* __restrict__ ald,
    const float* __restrict__ w2, const float* __restrict__ b2,
    float* __restrict__ escore)
{
    __shared__ _Float16 w_lds[128 * 136];   // 34.8 KB
    __shared__ _Float16 a_lds[64 * 136];    // 17.4 KB
    int t = threadIdx.x;
    int KP = K + 8;
    int K8 = K >> 3;

    // stage W once (coalesced)
    for (int i = t; i < 128 * K8; i += 256) {
        int row = i / K8, c8 = i - row * K8;
        *(f16x8*)&w_lds[row * KP + 8 * c8] = *(const f16x8*)&Wt[(size_t)row * K + 8 * c8];
    }

    int lane = t & 63, wv = t >> 6;
    int l15 = lane & 15, quad = lane >> 4;

    for (int tile = 0; tile < 2; ++tile) {
        int n0 = blockIdx.x * 128 + tile * 64;
        if (n0 >= N) break;
        __syncthreads();   // W ready (tile 0) / previous epilogue done with a_lds
        // stage A (coalesced)
        for (int i = t; i < 64 * K8; i += 256) {
            int row = i / K8, c8 = i - row * K8;
            f16x8 v = {};
            if (n0 + row < N) v = *(const f16x8*)&A16[(size_t)(n0 + row) * K + 8 * c8];
            *(f16x8*)&a_lds[row * KP + 8 * c8] = v;
        }
        __syncthreads();

        f32x4 acc[8];
#pragma unroll
        for (int c = 0; c < 8; ++c) acc[c] = (f32x4){0.f, 0.f, 0.f, 0.f};

        int ksteps = K >> 5;
        for (int kk = 0; kk < ksteps; ++kk) {
            f16x8 af = *(const f16x8*)&a_lds[(wv * 16 + l15) * KP + kk * 32 + quad * 8];
#pragma unroll
            for (int c = 0; c < 8; ++c) {
                f16x8 bf = *(const f16x8*)&w_lds[(c * 16 + l15) * KP + kk * 32 + quad * 8];
                acc[c] = __builtin_amdgcn_mfma_f32_16x16x32_f16(af, bf, acc[c], 0, 0, 0);
            }
        }

        // C layout: row = wv*16 + quad*4 + r, col = c*16 + l15
        if (mode == 0) {
            float bv[8];
#pragma unroll
            for (int c = 0; c < 8; ++c) bv[c] = bias[c * 16 + l15];
            __syncthreads();
#pragma unroll
            for (int r = 0; r < 4; ++r) {
                int n = n0 + wv * 16 + quad * 4 + r;
                int nt = (n < N) ? ntypes[n] : 0;
#pragma unroll
                for (int c = 0; c < 8; ++c)
                    a_lds[(wv * 16 + quad * 4 + r) * 136 + c * 16 + l15] =
                        (_Float16)(acc[c][r] + bv[c] + nemb[nt * HID + c * 16 + l15]);
            }
            __syncthreads();
            for (int i = t; i < 64 * 16; i += 256) {
                int row = i >> 4, c8 = i & 15;
                int n = n0 + row;
                if (n < N) *(f16x8*)&h16out[(size_t)n * HID + 8 * c8] = *(const f16x8*)&a_lds[row * 136 + 8 * c8];
            }
        } else if (mode == 1) {
            __syncthreads();
#pragma unroll
            for (int c = 0; c < 8; ++c)
#pragma unroll
                for (int r = 0; r < 4; ++r)
                    a_lds[(wv * 16 + quad * 4 + r) * 136 + c * 16 + l15] = (_Float16)acc[c][r];
            __syncthreads();
            // hp16 store (coalesced 16B)
            for (int i = t; i < 64 * 16; i += 256) {
                int row = i >> 4, c8 = i & 15;
                int n = n0 + row;
                if (n < N) *(f16x8*)&hp_out[(size_t)n * HID + 8 * c8] = *(const f16x8*)&a_lds[row * 136 + 8 * c8];
            }
            // als/ald from LDS transpose: task = row*8 + head
            for (int task = t; task < 512; task += 256) {
                int row = task >> 3, hd = task & 7;
                int n = n0 + row;
                if (n >= N) continue;
                f16x8 v0 = *(const f16x8*)&a_lds[row * 136 + hd * 16];
                f16x8 v1 = *(const f16x8*)&a_lds[row * 136 + hd * 16 + 8];
                float va = 0.f, vd = 0.f;
#pragma unroll
                for (int j = 0; j < 8; ++j) {
                    va += (float)v0[j] * asrc[hd * 16 + j] + (float)v1[j] * asrc[hd * 16 + 8 + j];
                    vd += (float)v0[j] * adst[hd * 16 + j] + (float)v1[j] * adst[hd * 16 + 8 + j];
                }
                als[n * HEADS + hd] = va;
                ald[n * HEADS + hd] = vd;
            }
        } else {
            float b2v = b2[0];
            float treg[4] = {0.f, 0.f, 0.f, 0.f};
#pragma unroll
            for (int c = 0; c < 8; ++c) {
                float b1v = bias[c * 16 + l15];
                float w2v = w2[c * 16 + l15];
#pragma unroll
                for (int r = 0; r < 4; ++r)
                    treg[r] += fast_tanh(acc[c][r] + b1v) * w2v;
            }
#pragma unroll
            for (int r = 0; r < 4; ++r) {
                float v = treg[r];
#pragma unroll
                for (int m = 8; m >= 1; m >>= 1) v += __shfl_xor(v, m, 64);
                if (l15 == 0) {
                    int n = n0 + wv * 16 + quad * 4 + r;
                    if (n < N) escore[n] = __expf(v + b2v);
                }
            }
        }
    }
}

// ================= fused aggregate: 16 edges in flight, packed fdot2 =================
// lane = (edge-sub 0..3, chan-grp 0..15); each lane gathers 4x f16x8 per iteration.
__global__ void gat_aggregate_kernel(const int* __restrict__ rowptr, const int* __restrict__ esrc,
                                     const float* __restrict__ als, const float* __restrict__ ald,
                                     const _Float16* __restrict__ hp16, const float* __restrict__ gb,
                                     const float* __restrict__ lg, const float* __restrict__ lb,
                                     _Float16* __restrict__ h16, int N) {
    int wave = threadIdx.x >> 6;
    int lane = threadIdx.x & 63;
    int n = blockIdx.x * 4 + wave;
    if (n >= N) return;
    int esub = lane >> 4;          // 0..3
    int cg = lane & 15;            // channels cg*8 .. cg*8+7 (head cg>>1)
    int hd = cg >> 1;
    float adv = ald[n * HEADS + hd];
    int row = rowptr[n], end = rowptr[n + 1];   // end > row (self-loop)
    int last = end - 1;
    float acc[8] = {0.f, 0.f, 0.f, 0.f, 0.f, 0.f, 0.f, 0.f};
    float sw = 0.f;
    for (int base = row; base < end; base += 16) {
        int iA = base + esub;
        int iB = iA + 4, iC = iA + 8, iD = iA + 12;
        int cA = iA <= last ? iA : last;
        int cB = iB <= last ? iB : last;
        int cC = iC <= last ? iC : last;
        int cD = iD <= last ? iD : last;
        int sA = esrc[cA], sB = esrc[cB], sC = esrc[cC], sD = esrc[cD];
        f16x8 pA = *(const f16x8*)&hp16[(size_t)sA * HID + cg * 8];
        f16x8 pB = *(const f16x8*)&hp16[(size_t)sB * HID + cg * 8];
        f16x8 pC = *(const f16x8*)&hp16[(size_t)sC * HID + cg * 8];
        f16x8 pD = *(const f16x8*)&hp16[(size_t)sD * HID + cg * 8];
        float aA = als[sA * HEADS + hd];
        float aB = als[sB * HEADS + hd];
        float aC = als[sC * HEADS + hd];
        float aD = als[sD * HEADS + hd];
        float lA = aA + adv; lA = lA > 0.f ? lA : 0.2f * lA;
        float lB = aB + adv; lB = lB > 0.f ? lB : 0.2f * lB;
        float lC = aC + adv; lC = lC > 0.f ? lC : 0.2f * lC;
        float lD = aD + adv; lD = lD > 0.f ? lD : 0.2f * lD;
        float wA = __expf(lA) * ((iA < end) ? 1.f : 0.f);
        float wB = __expf(lB) * ((iB < end) ? 1.f : 0.f);
        float wC = __expf(lC) * ((iC < end) ? 1.f : 0.f);
        float wD = __expf(lD) * ((iD < end) ? 1.f : 0.f);
        sw += (wA + wB) + (wC + wD);
#ifdef HAVE_FDOT2
        f16x2 wAB; wAB[0] = (_Float16)wA; wAB[1] = (_Float16)wB;
        f16x2 wCD; wCD[0] = (_Float16)wC; wCD[1] = (_Float16)wD;
#pragma unroll
        for (int j = 0; j < 8; ++j) {
            f16x2 prAB; prAB[0] = pA[j]; prAB[1] = pB[j];
            f16x2 prCD; prCD[0] = pC[j]; prCD[1] = pD[j];
            acc[j] = __builtin_amdgcn_fdot2(prAB, wAB, acc[j], false);
            acc[j] = __builtin_amdgcn_fdot2(prCD, wCD, acc[j], false);
        }
#else
#pragma unroll
        for (int j = 0; j < 8; ++j)
            acc[j] += wA * (float)pA[j] + wB * (float)pB[j]
                    + wC * (float)pC[j] + wD * (float)pD[j];
#endif
    }
    // combine the 4 edge-subgroups (lane bits 4,5)
#pragma unroll
    for (int m = 16; m <= 32; m <<= 1) {
        sw += __shfl_xor(sw, m, 64);
#pragma unroll
        for (int j = 0; j < 8; ++j) acc[j] += __shfl_xor(acc[j], m, 64);
    }
    float inv_sw = 1.f / sw;
    float4 g0 = ((const float4*)(gb + cg * 8))[0];
    float4 g1 = ((const float4*)(gb + cg * 8))[1];
    float v[8];
    v[0] = acc[0] * inv_sw + g0.x; v[1] = acc[1] * inv_sw + g0.y;
    v[2] = acc[2] * inv_sw + g0.z; v[3] = acc[3] * inv_sw + g0.w;
    v[4] = acc[4] * inv_sw + g1.x; v[5] = acc[5] * inv_sw + g1.y;
    v[6] = acc[6] * inv_sw + g1.z; v[7] = acc[7] * inv_sw + g1.w;
    // layernorm: each channel appears 4x across the wave -> /512
    float s = 0.f;
#pragma unroll
    for (int j = 0; j < 8; ++j) s += v[j];
#pragma unroll
    for (int m = 32; m >= 1; m >>= 1) s += __shfl_xor(s, m, 64);
    float mu = s * (1.f / 512.f);
    float d[8], sq = 0.f;
#pragma unroll
    for (int j = 0; j < 8; ++j) { d[j] = v[j] - mu; sq += d[j] * d[j]; }
#pragma unroll
    for (int m = 32; m >= 1; m >>= 1) sq += __shfl_xor(sq, m, 64);
    float inv = rsqrtf(sq * (1.f / 512.f) + 1e-5f);
    float4 lg0 = ((const float4*)(lg + cg * 8))[0];
    float4 lg1 = ((const float4*)(lg + cg * 8))[1];
    float4 lb0 = ((const float4*)(lb + cg * 8))[0];
    float4 lb1 = ((const float4*)(lb + cg * 8))[1];
    float lgv[8] = {lg0.x, lg0.y, lg0.z, lg0.w, lg1.x, lg1.y, lg1.z, lg1.w};
    float lbv[8] = {lb0.x, lb0.y, lb0.z, lb0.w, lb1.x, lb1.y, lb1.z, lb1.w};
    f16x8 hold = *(const f16x8*)&h16[(size_t)n * HID + cg * 8];
    f16x8 hnew;
#pragma unroll
    for (int j = 0; j < 8; ++j) {
        float r = d[j] * inv * lgv[j] + lbv[j] + (float)hold[j];
        hnew[j] = (_Float16)(r > 0.f ? r : 0.f);
    }
    if (esub == 0) *(f16x8*)&h16[(size_t)n * HID + cg * 8] = hnew;
}

// ================= per-graph pooling (h16) =================
__global__ void pool_graph_kernel(const _Float16* __restrict__ h16, const float* __restrict__ escore,
                                  const int* __restrict__ gstart, float* __restrict__ sums,
                                  float* __restrict__ cnts, float* __restrict__ hgZ, int G) {
    int g = blockIdx.x;
    int t = threadIdx.x;               // 0..511
    int c = t & 127, grp = t >> 7;     // 4 groups
    int s = gstart[g], e = gstart[g + 1];
    float msum = 0.f, asum = 0.f, z = 0.f;
    for (int n = s + grp; n < e; n += 4) {
        float hv = (float)h16[(size_t)n * HID + c];
        float es = escore[n];
        msum += hv;
        asum += es * hv;
        if (c == 0) z += es;
    }
    __shared__ float sm[4][HID];
    __shared__ float sa[4][HID];
    __shared__ float sz[4];
    sm[grp][c] = msum;
    sa[grp][c] = asum;
    if (c == 0) sz[grp] = z;
    __syncthreads();
    if (t < HID) {
        float m = sm[0][t] + sm[1][t] + sm[2][t] + sm[3][t];
        float a = sa[0][t] + sa[1][t] + sa[2][t] + sa[3][t];
        sums[(size_t)g * HID + t] = m;
        atomicAdd(&hgZ[t], a);
    } else if (t == HID) {
        cnts[g] = (float)(e - s);
        atomicAdd(&hgZ[HID], sz[0] + sz[1] + sz[2] + sz[3]);
    }
}

// ================= classifier head =================
__global__ void head_kernel(const float* __restrict__ hgZ, const float* __restrict__ sums,
                            const float* __restrict__ cnts, const float* __restrict__ W1,
                            const float* __restrict__ b1, const float* __restrict__ W2,
                            const float* __restrict__ b2, float* __restrict__ out, int G) {
    int g = blockIdx.x;
    int t = threadIdx.x;
    __shared__ float hr[HID];
    __shared__ float part[2];
    float Z = hgZ[HID];
    float cnt = cnts[g];
    cnt = cnt > 1.f ? cnt : 1.f;
    hr[t] = hgZ[t] / Z + sums[(size_t)g * HID + t] / cnt;
    __syncthreads();
    float acc = b1[t];
#pragma unroll 8
    for (int k = 0; k < HID; ++k) acc += hr[k] * W1[k * HID + t];
    acc = acc > 0.f ? acc : 0.f;
    float v = acc * W2[t];
#pragma unroll
    for (int m = 32; m >= 1; m >>= 1) v += __shfl_xor(v, m, 64);
    if ((t & 63) == 0) part[t >> 6] = v;
    __syncthreads();
    if (t == 0) out[g] = part[0] + part[1] + b2[0];
}

extern "C" void kernel_launch(void* const* d_in, const int* in_sizes, int n_in,
                              void* d_out, int out_size, void* d_ws, size_t ws_size,
                              hipStream_t stream) {
    const float* x        = (const float*)d_in[0];
    const int*   ei       = (const int*)d_in[1];
    const int*   ntypes   = (const int*)d_in[2];
    const int*   batch    = (const int*)d_in[3];
    const float* emb_W    = (const float*)d_in[4];
    const float* emb_b    = (const float*)d_in[5];
    const float* nemb     = (const float*)d_in[6];
    const float* gat_W    = (const float*)d_in[7];
    const float* att_src  = (const float*)d_in[8];
    const float* att_dst  = (const float*)d_in[9];
    const float* gat_b    = (const float*)d_in[10];
    const float* ln_g     = (const float*)d_in[11];
    const float* ln_b     = (const float*)d_in[12];
    const float* ga_W1    = (const float*)d_in[13];
    const float* ga_b1    = (const float*)d_in[14];
    const float* ga_W2    = (const float*)d_in[15];
    const float* ga_b2    = (const float*)d_in[16];
    const float* cls_W1   = (const float*)d_in[17];
    const float* cls_b1   = (const float*)d_in[18];
    const float* cls_W2   = (const float*)d_in[19];
    const float* cls_b2   = (const float*)d_in[20];
    float* out = (float*)d_out;

    const int N  = in_sizes[2];
    const int E  = in_sizes[1] / 2;
    const int EE = E + N;
    const int G  = out_size;
    const int NB = (N + 255) / 256;
    const int XT4 = N * INDIM / 4;

    float* ws      = (float*)d_ws;
    float* als     = ws;                               // N*8
    float* ald     = als + (size_t)N * HEADS;          // N*8
    float* escore  = ald + (size_t)N * HEADS;          // N
    float* sums    = escore + N;                       // G*128
    float* cnts    = sums + (size_t)G * HID;           // G
    float* hgZ     = cnts + G;                         // 129
    _Float16* h16  = (_Float16*)(hgZ + HID + 1);       // N*128
    _Float16* hp16 = h16 + (size_t)N * HID;            // N*128
    _Float16* x16  = hp16 + (size_t)N * HID;           // N*64
    _Float16* wt_emb = x16 + (size_t)N * INDIM;        // 128*64
    _Float16* wt_gat = wt_emb + 128 * 64;              // 3*128*128
    _Float16* wt_ga1 = wt_gat + 3 * 128 * 128;         // 128*128
    int*   rowptr  = (int*)(wt_ga1 + 128 * 128);       // N+1
    int*   woff    = rowptr + (N + 1);                 // N
    int*   deg     = woff + N;                         // N
    int*   esrc    = deg + N;                          // EE
    int*   partials= esrc + EE;                        // NB
    int*   gstart  = partials + NB;                    // G+1

    // ---- prologue: deg zero, then fused count/converts/gstart/hgZ-zero ----
    hipMemsetAsync(deg, 0, (size_t)N * sizeof(int), stream);
    int ptot = XT4 > EE ? XT4 : EE;
    if (ptot < 100000 + G + 1) ptot = 100000 + G + 1;
    prologue_kernel<<<(ptot + 255) / 256, 256, 0, stream>>>(
        ei, deg, x, x16, emb_W, gat_W, ga_W1, wt_emb, wt_gat, wt_ga1,
        batch, gstart, hgZ, E, EE, N, G, XT4);
    block_sum_kernel<<<NB, 256, 0, stream>>>(deg, partials, N);
    scan_partials_kernel<<<1, 64, 0, stream>>>(partials, NB);
    rowptr_kernel<<<NB, 256, 0, stream>>>(deg, partials, rowptr, woff, N, EE);
    scatter_kernel<<<(EE + 255) / 256, 256, 0, stream>>>(ei, woff, esrc, E, EE);

    const int PB = (N + 127) / 128;   // 2 tiles of 64 per block

    // ---- network ----
    mfma_proj_kernel<<<PB, 256, 0, stream>>>(
        0, INDIM, N, x16, wt_emb, emb_b, nemb, ntypes, h16,
        nullptr, nullptr, nullptr, nullptr, nullptr, nullptr, nullptr, nullptr);

    for (int l = 0; l < 3; ++l) {
        mfma_proj_kernel<<<PB, 256, 0, stream>>>(
            1, HID, N, h16, wt_gat + (size_t)l * HID * HID,
            nullptr, nullptr, nullptr, nullptr,
            att_src + l * HID, att_dst + l * HID,
            hp16, als, ald, nullptr, nullptr, nullptr);
        gat_aggregate_kernel<<<(N + 3) / 4, 256, 0, stream>>>(
            rowptr, esrc, als, ald, hp16,
            gat_b + l * HID, ln_g + l * HID, ln_b + l * HID, h16, N);
    }

    mfma_proj_kernel<<<PB, 256, 0, stream>>>(
        2, HID, N, h16, wt_ga1, ga_b1, nullptr, nullptr, nullptr,
        nullptr, nullptr, nullptr, nullptr, nullptr, ga_W2, ga_b2, escore);

    pool_graph_kernel<<<G, 512, 0, stream>>>(h16, escore, gstart, sums, cnts, hgZ, G);
    head_kernel<<<G, 128, 0, stream>>>(hgZ, sums, cnts, cls_W1, cls_b1, cls_W2, cls_b2, out, G);
}